// Round 13
// baseline (2620.639 us; speedup 1.0000x reference)
//
#include <hip/hip_runtime.h>
#include <math.h>
#include <stdint.h>

// NSTransformer forward. bf16-MFMA GEMMs: 128x128 tile with 4-buffer LDS
// pipeline + counted vmcnt (never 0) + raw barriers (T4 mechanism, m218),
// bf16 residual stream, fused QKV, row-19 last layer, balanced chunks, XCD swizzle.
#define BB 4096
#define LL 20
#define FE 20
#define DD 512
#define HH 8
#define DHD 64
#define FFD 2048
#define NLAY 3

typedef __bf16 bf16x8 __attribute__((ext_vector_type(8)));
typedef float f32x4 __attribute__((ext_vector_type(4)));

// Direct C-style casts (addrspacecast) — NOT via uintptr_t (round-3 abort cause).
__device__ __forceinline__ void gload_lds16(const unsigned short* g, unsigned short* l){
  __builtin_amdgcn_global_load_lds(
      (const __attribute__((address_space(1))) void*)g,
      (__attribute__((address_space(3))) void*)l, 16, 0, 0);
}

__device__ __forceinline__ float wsum(float v){
#pragma unroll
  for (int o = 32; o > 0; o >>= 1) v += __shfl_xor(v, o, 64);
  return v;
}

__device__ __forceinline__ unsigned short f2b(float f){
  unsigned u = __float_as_uint(f);
  u += 0x7FFFu + ((u >> 16) & 1u);
  return (unsigned short)(u >> 16);
}
__device__ __forceinline__ float b2f(unsigned short b){
  return __uint_as_float(((unsigned)b) << 16);
}

// XCD-aware bijective block swizzle (m204).
__device__ __forceinline__ int2 xcd_swz(){
  const int nx = gridDim.x;
  const int nwg = nx * gridDim.y;
  const int orig = blockIdx.y * nx + blockIdx.x;
  const int q = nwg >> 3, r = nwg & 7;
  const int xcd = orig & 7, idx = orig >> 3;
  const int wg = (xcd < r ? xcd*(q+1) : r*(q+1) + (xcd-r)*q) + idx;
  return make_int2(wg % nx, wg / nx);
}

// ============ bf16 MFMA GEMM, 128x128 tile, 4-buffer counted-vmcnt pipeline ============
// Correctness: buffer (t+3)&3 is dead (read in iter t-1, reads drained before that
// iter's end barrier) when stage(t+3) issues in iter t. vmcnt(8) at iter start
// retires the 4 oldest outstanding loads = stage(t) (in-order retirement, m135);
// barrier makes it collective. Stages t+1,t+2 (8 loads) stay in flight across
// barriers — the T4 property. Tail: clamped re-stage into the dead buffer keeps
// the count arithmetic uniform. Requires nt >= 3 (all uses have K >= 512).
template<bool RELU, bool BIAS, bool RES>
__global__ __launch_bounds__(256) void bgemm(
    const unsigned short* __restrict__ A, int lda,
    const unsigned short* __restrict__ W, int ldw,
    const float* __restrict__ bias,
    const unsigned short* res, int ldr,
    unsigned short* __restrict__ Cout, int ldc, int K)
{
  __shared__ __align__(16) unsigned short Asm[4][128*32];
  __shared__ __align__(16) unsigned short Bsm[4][128*32];
  const int2 swz = xcd_swz();
  const int bn = swz.x << 7, bm = swz.y << 7;
  const int tid = threadIdx.x;
  const int wave = tid >> 6, lane = tid & 63;
  const int wr = wave >> 1, wc = wave & 1;
  const int sr = lane >> 2, slot = lane & 3;
  const int rg = lane & 15, cg = lane >> 4;

  f32x4 acc[4][4];
#pragma unroll
  for (int i = 0; i < 4; ++i)
#pragma unroll
    for (int j = 0; j < 4; ++j) acc[i][j] = (f32x4){0.f,0.f,0.f,0.f};

  auto stageA = [&](int kt, int b){
    const int k0 = kt << 5;
#pragma unroll
    for (int i = 0; i < 2; ++i) {
      const int r  = (i<<6) + (wave<<4) + sr;
      const int ch = slot ^ ((r>>1)&3);
      gload_lds16(A + (size_t)(bm + r)*lda + k0 + (ch<<3),
                  &Asm[b][((i<<6) + (wave<<4))*32]);
    }
  };
  auto stageB = [&](int kt, int b){
    const int k0 = kt << 5;
#pragma unroll
    for (int i = 0; i < 2; ++i) {
      const int r  = (i<<6) + (wave<<4) + sr;
      const int ch = slot ^ ((r>>1)&3);
      gload_lds16(W + (size_t)(bn + r)*ldw + k0 + (ch<<3),
                  &Bsm[b][((i<<6) + (wave<<4))*32]);
    }
  };

  const int nt = K >> 5;
  // prologue: stage K-tiles 0,1,2 into buffers 0,1,2 (12 loads outstanding)
  stageA(0, 0); stageB(0, 0);
  stageA(1, 1); stageB(1, 1);
  stageA(2, 2); stageB(2, 2);

  for (int t = 0; t < nt; ++t){
    // per-wave: stage(t) landed (<=8 outstanding = stages t+1,t+2); then collective.
    asm volatile("s_waitcnt vmcnt(8)" ::: "memory");
    __builtin_amdgcn_s_barrier();
    __builtin_amdgcn_sched_barrier(0);
    asm volatile("" ::: "memory");

    const int cb = t & 3;
    const int ts = (t + 3 < nt) ? t + 3 : nt - 1;   // clamped tail re-stage
    const int sb = (t + 3) & 3;

    bf16x8 af[4], bfr[4];
#pragma unroll
    for (int mi = 0; mi < 4; ++mi){
      int r = (wr<<6) + (mi<<4) + rg;
      af[mi] = *(const bf16x8*)&Asm[cb][r*32 + ((cg ^ ((r>>1)&3))<<3)];
    }
#pragma unroll
    for (int ni = 0; ni < 4; ++ni){
      int r = (wc<<6) + (ni<<4) + rg;
      bfr[ni] = *(const bf16x8*)&Bsm[cb][r*32 + ((cg ^ ((r>>1)&3))<<3)];
    }
    // issue next stage while reads/MFMA proceed (lands >= 3 iterations later)
    stageA(ts, sb);
    stageB(ts, sb);

    __builtin_amdgcn_s_setprio(1);
#pragma unroll
    for (int mi = 0; mi < 4; ++mi)
#pragma unroll
      for (int ni = 0; ni < 4; ++ni)
        acc[mi][ni] = __builtin_amdgcn_mfma_f32_16x16x32_bf16(af[mi], bfr[ni], acc[mi][ni], 0, 0, 0);
    __builtin_amdgcn_s_setprio(0);

    asm volatile("" ::: "memory");
    __builtin_amdgcn_sched_barrier(0);
    __builtin_amdgcn_s_barrier();
  }

#pragma unroll
  for (int mi = 0; mi < 4; ++mi){
#pragma unroll
    for (int ni = 0; ni < 4; ++ni){
      const int row0 = bm + (wr<<6) + (mi<<4) + (cg<<2);
      const int col  = bn + (wc<<6) + (ni<<4) + rg;
      float bv = BIAS ? bias[col] : 0.f;
#pragma unroll
      for (int j = 0; j < 4; ++j){
        float v = acc[mi][ni][j] + bv;
        if (RES)  v += b2f(res[(size_t)(row0+j)*ldr + col]);
        if (RELU) v = fmaxf(v, 0.f);
        Cout[(size_t)(row0+j)*ldc + col] = f2b(v);
      }
    }
  }
}

// ============ bf16 MFMA GEMM, 64x128 tile (row-19 tail; proven 2-phase) ============
template<bool RELU, bool BIAS, bool RES>
__global__ __launch_bounds__(256) void bgemm64(
    const unsigned short* __restrict__ A, int lda,
    const unsigned short* __restrict__ W, int ldw,
    const float* __restrict__ bias,
    const unsigned short* res, int ldr,
    unsigned short* __restrict__ Cout, int ldc, int K)
{
  __shared__ __align__(16) unsigned short Asm[2][64*32];
  __shared__ __align__(16) unsigned short Bsm[2][128*32];
  const int2 swz = xcd_swz();
  const int bn = swz.x << 7, bm = swz.y << 6;
  const int tid = threadIdx.x;
  const int wave = tid >> 6, lane = tid & 63;
  const int sr = lane >> 2, slot = lane & 3;
  const int rg = lane & 15, cg = lane >> 4;

  f32x4 acc[4][2];
#pragma unroll
  for (int i = 0; i < 4; ++i)
#pragma unroll
    for (int j = 0; j < 2; ++j) acc[i][j] = (f32x4){0.f,0.f,0.f,0.f};

  auto stage = [&](int kt, int b){
    const int k0 = kt << 5;
    {
      const int r  = (wave<<4) + sr;
      const int ch = slot ^ ((r>>1)&3);
      gload_lds16(A + (size_t)(bm + r)*lda + k0 + (ch<<3),
                  &Asm[b][(wave<<4)*32]);
    }
#pragma unroll
    for (int i = 0; i < 2; ++i) {
      const int r  = (i<<6) + (wave<<4) + sr;
      const int ch = slot ^ ((r>>1)&3);
      gload_lds16(W + (size_t)(bn + r)*ldw + k0 + (ch<<3),
                  &Bsm[b][((i<<6) + (wave<<4))*32]);
    }
  };

  auto compute = [&](int b){
    bf16x8 af[4], bfr[2];
#pragma unroll
    for (int mi = 0; mi < 4; ++mi){
      int r = (mi<<4) + rg;
      af[mi] = *(const bf16x8*)&Asm[b][r*32 + ((cg ^ ((r>>1)&3))<<3)];
    }
#pragma unroll
    for (int ni = 0; ni < 2; ++ni){
      int r = (wave<<5) + (ni<<4) + rg;
      bfr[ni] = *(const bf16x8*)&Bsm[b][r*32 + ((cg ^ ((r>>1)&3))<<3)];
    }
#pragma unroll
    for (int mi = 0; mi < 4; ++mi)
#pragma unroll
      for (int ni = 0; ni < 2; ++ni)
        acc[mi][ni] = __builtin_amdgcn_mfma_f32_16x16x32_bf16(af[mi], bfr[ni], acc[mi][ni], 0, 0, 0);
  };

  const int nt = K >> 5;
  stage(0, 0);
  __syncthreads();
  int cur = 0;
  for (int t = 0; t < nt; ++t){
    if (t + 1 < nt) stage(t + 1, cur ^ 1);
    compute(cur);
    __syncthreads();
    cur ^= 1;
  }

#pragma unroll
  for (int mi = 0; mi < 4; ++mi){
#pragma unroll
    for (int ni = 0; ni < 2; ++ni){
      const int row0 = bm + (mi<<4) + (cg<<2);
      const int col  = bn + (wave<<5) + (ni<<4) + rg;
      float bv = BIAS ? bias[col] : 0.f;
#pragma unroll
      for (int j = 0; j < 4; ++j){
        float v = acc[mi][ni][j] + bv;
        if (RES)  v += b2f(res[(size_t)(row0+j)*ldr + col]);
        if (RELU) v = fmaxf(v, 0.f);
        Cout[(size_t)(row0+j)*ldc + col] = f2b(v);
      }
    }
  }
}

// ============ fp32 tiled GEMM (projector fp32 out; embed PE -> bf16-only out) ============
template<bool RELU, bool BIAS, bool PE>
__global__ __launch_bounds__(256) void gemm_xwt(
    const float* __restrict__ A, int lda,
    const float* __restrict__ W, int ldw,
    const float* __restrict__ bias,
    float* __restrict__ C, int ldc,
    int M, int N, int K,
    const float* __restrict__ pe, unsigned short* __restrict__ xbout)
{
  __shared__ float As[16][72];
  __shared__ float Ws[16][72];
  const int bm = blockIdx.y << 6, bn = blockIdx.x << 6;
  const int tid = threadIdx.x;
  const int tx = tid & 15, ty = tid >> 4;
  const int lr = tid >> 2;
  const int lc = (tid & 3) << 2;
  float acc[4][4] = {{0.f}};
  const float* Ap = A + (size_t)(bm + lr) * lda;
  const float* Wp = W + (size_t)(bn + lr) * ldw;
  for (int k0 = 0; k0 < K; k0 += 16) {
    float4 av, wv;
    if (k0 + 16 <= K) {
      av = *(const float4*)(Ap + k0 + lc);
      wv = *(const float4*)(Wp + k0 + lc);
    } else {
      float aa[4] = {0,0,0,0}, ww[4] = {0,0,0,0};
#pragma unroll
      for (int j = 0; j < 4; ++j){ int kk = k0 + lc + j; if (kk < K){ aa[j] = Ap[kk]; ww[j] = Wp[kk]; } }
      av = make_float4(aa[0],aa[1],aa[2],aa[3]);
      wv = make_float4(ww[0],ww[1],ww[2],ww[3]);
    }
    As[lc+0][lr]=av.x; As[lc+1][lr]=av.y; As[lc+2][lr]=av.z; As[lc+3][lr]=av.w;
    Ws[lc+0][lr]=wv.x; Ws[lc+1][lr]=wv.y; Ws[lc+2][lr]=wv.z; Ws[lc+3][lr]=wv.w;
    __syncthreads();
#pragma unroll
    for (int k = 0; k < 16; ++k) {
      const float4 a = *(const float4*)(&As[k][ty<<2]);
      const float4 b = *(const float4*)(&Ws[k][tx<<2]);
      acc[0][0]+=a.x*b.x; acc[0][1]+=a.x*b.y; acc[0][2]+=a.x*b.z; acc[0][3]+=a.x*b.w;
      acc[1][0]+=a.y*b.x; acc[1][1]+=a.y*b.y; acc[1][2]+=a.y*b.z; acc[1][3]+=a.y*b.w;
      acc[2][0]+=a.z*b.x; acc[2][1]+=a.z*b.y; acc[2][2]+=a.z*b.z; acc[2][3]+=a.z*b.w;
      acc[3][0]+=a.w*b.x; acc[3][1]+=a.w*b.y; acc[3][2]+=a.w*b.z; acc[3][3]+=a.w*b.w;
    }
    __syncthreads();
  }
#pragma unroll
  for (int i = 0; i < 4; ++i) {
    const int m = bm + (ty<<2) + i;
#pragma unroll
    for (int j = 0; j < 4; ++j) {
      const int col = bn + (tx<<2) + j;
      float v = acc[i][j];
      if (BIAS) v += bias[col];
      if (PE)   v += pe[(m % LL)*DD + col];
      if (RELU) v = fmaxf(v, 0.f);
      if (PE) xbout[(size_t)m*ldc + col] = f2b(v);
      else    C[(size_t)m*ldc + col] = v;
    }
  }
}

// ============ misc small kernels ============
__global__ void cvt_bf16_kernel(const float* __restrict__ in, unsigned short* __restrict__ out, int n){
  int i = blockIdx.x * 256 + threadIdx.x;
  if (i < n) out[i] = f2b(in[i]);
}

__global__ void concat_bias_kernel(const float* __restrict__ bq, const float* __restrict__ bk,
                                   const float* __restrict__ bv, float* __restrict__ bqkv){
  int i = blockIdx.x * 256 + threadIdx.x;
  if (i >= NLAY*1536) return;
  int l = i / 1536, r = i % 1536;
  int s = r >> 9, j = r & 511;
  const float* srcp = (s == 0) ? bq : (s == 1) ? bk : bv;
  bqkv[i] = srcp[l*DD + j];
}

__global__ void pe_kernel(float* __restrict__ pe){
  int i = blockIdx.x * 256 + threadIdx.x;
  int l = i >> 8, hd = i & 255;
  float dv = expf((2.f * hd) * (-9.210340371976184f / 512.f));
  float a = (float)l * dv;
  pe[l*DD + 2*hd]     = sinf(a);
  pe[l*DD + 2*hd + 1] = cosf(a);
}

__global__ void stats_kernel(const float* __restrict__ src, float* __restrict__ mean,
                             float* __restrict__ stdv, int nbf){
  int i = blockIdx.x * 256 + threadIdx.x;
  if (i >= nbf) return;
  int b = i / FE, f = i % FE;
  const float* p = src + (size_t)b * (LL*FE) + f;
  float v[LL]; float s = 0.f;
#pragma unroll
  for (int l = 0; l < LL; ++l){ v[l] = p[l*FE]; s += v[l]; }
  float m = s * (1.f/LL);
  float q = 0.f;
#pragma unroll
  for (int l = 0; l < LL; ++l){ float d = v[l]-m; q += d*d; }
  mean[i] = m;
  stdv[i] = sqrtf(q * (1.f/LL) + 1e-5f);
}

__global__ void snorm_kernel(const float* __restrict__ src, const float* __restrict__ mean,
                             const float* __restrict__ stdv, float* __restrict__ s, int n){
  int i = blockIdx.x * 256 + threadIdx.x;
  if (i >= n) return;
  int b = i / (LL*FE);
  int f = i % FE;
  int bf = b*FE + f;
  s[i] = (src[i] - mean[bf]) / stdv[bf];
}

__global__ __launch_bounds__(64) void convz_kernel(
    const float* __restrict__ src, const float* __restrict__ wt, const float* __restrict__ wd,
    const float* __restrict__ mean, const float* __restrict__ stdv,
    float* __restrict__ z_tau, float* __restrict__ z_del)
{
  int b = blockIdx.x;
  __shared__ float ss[LL*FE];
  __shared__ float wct[LL*3], wcd[LL*3];
  for (int idx = threadIdx.x; idx < LL*FE; idx += 64) ss[idx] = src[(size_t)b*LL*FE + idx];
  if (threadIdx.x < 60){ wct[threadIdx.x] = wt[threadIdx.x]; wcd[threadIdx.x] = wd[threadIdx.x]; }
  __syncthreads();
  if (threadIdx.x < 40) {
    int f = threadIdx.x % FE;
    bool isdel = threadIdx.x >= FE;
    const float* w = isdel ? wcd : wct;
    int fm = (f + FE - 1) % FE, fp = (f + 1) % FE;
    float acc = 0.f;
#pragma unroll
    for (int t = 0; t < LL; ++t){
      const float* r = ss + t*FE;
      acc += r[fm]*w[t*3+0] + r[f]*w[t*3+1] + r[fp]*w[t*3+2];
    }
    if (isdel){ z_del[b*40 + f] = acc; z_del[b*40 + 20 + f] = mean[b*FE + f]; }
    else      { z_tau[b*40 + f] = acc; z_tau[b*40 + 20 + f] = stdv[b*FE + f]; }
  }
}

__global__ __launch_bounds__(256) void tau_head(const float* __restrict__ h, const float* __restrict__ W2, float* __restrict__ tau){
  const int b = (blockIdx.x << 2) + (threadIdx.x >> 6);
  const int lane = threadIdx.x & 63;
  const float* hb = h + (size_t)b * DD;
  float s = 0.f;
#pragma unroll
  for (int j = 0; j < 8; ++j){ int d0 = lane + j*64; s += hb[d0]*W2[d0]; }
  s = wsum(s);
  if (lane == 0) tau[b] = expf(s);
}

__global__ __launch_bounds__(256) void delta_head(const float* __restrict__ h, const float* __restrict__ W2, float* __restrict__ delta){
  const int b = blockIdx.x;
  const int w = threadIdx.x >> 6, lane = threadIdx.x & 63;
  const float* hb = h + (size_t)b * DD;
  for (int f = w; f < FE; f += 4){
    float s = 0.f;
#pragma unroll
    for (int j = 0; j < 8; ++j){ int d0 = lane + j*64; s += hb[d0]*W2[(size_t)f*DD + d0]; }
    s = wsum(s);
    if (lane == 0) delta[b*FE + f] = s;
  }
}

// ============ attention (full, layers 0..NLAY-2); o IN PLACE over q ============
__global__ __launch_bounds__(256) void attn_kernel(
    unsigned short* __restrict__ qkv,
    const float* __restrict__ tau, const float* __restrict__ delta)
{
  const int bh = blockIdx.x;
  const int b = bh >> 3, h = bh & 7;
  __shared__ float qs[LL][68];
  __shared__ float kt[DHD][25];
  __shared__ float vs[LL][DHD];
  __shared__ float ps[LL][LL+1];
  const size_t base = (size_t)b * LL * 1536 + h * DHD;
  unsigned short* qg = qkv + base;
  const unsigned short* kg = qkv + base + 512;
  const unsigned short* vg = qkv + base + 1024;

  for (int it = threadIdx.x; it < LL*16; it += 256) {
    const int l = it >> 4, c = it & 15;
    const ushort4 qv = *(const ushort4*)(qg + l*1536 + c*4);
    const ushort4 kv = *(const ushort4*)(kg + l*1536 + c*4);
    const ushort4 vv = *(const ushort4*)(vg + l*1536 + c*4);
    qs[l][c*4+0]=b2f(qv.x); qs[l][c*4+1]=b2f(qv.y); qs[l][c*4+2]=b2f(qv.z); qs[l][c*4+3]=b2f(qv.w);
    kt[c*4+0][l]=b2f(kv.x); kt[c*4+1][l]=b2f(kv.y); kt[c*4+2][l]=b2f(kv.z); kt[c*4+3][l]=b2f(kv.w);
    vs[l][c*4+0]=b2f(vv.x); vs[l][c*4+1]=b2f(vv.y); vs[l][c*4+2]=b2f(vv.z); vs[l][c*4+3]=b2f(vv.w);
  }
  __syncthreads();

  const float ta = tau[b];
  for (int idx = threadIdx.x; idx < LL*LL; idx += 256) {
    const int l = idx / LL, s2 = idx % LL;
    float d = 0.f;
#pragma unroll
    for (int e = 0; e < DHD; ++e) d += qs[l][e]*kt[e][s2];
    ps[l][s2] = 0.125f * (d * ta + delta[b*FE + s2]);
  }
  __syncthreads();

  if (threadIdx.x < LL) {
    const int l = threadIdx.x;
    float m = -1e30f;
#pragma unroll
    for (int s2 = 0; s2 < LL; ++s2) m = fmaxf(m, ps[l][s2]);
    float sum = 0.f;
#pragma unroll
    for (int s2 = 0; s2 < LL; ++s2){ float e2 = expf(ps[l][s2]-m); ps[l][s2] = e2; sum += e2; }
    const float r = 1.f / sum;
#pragma unroll
    for (int s2 = 0; s2 < LL; ++s2) ps[l][s2] *= r;
  }
  __syncthreads();

  for (int it = threadIdx.x; it < LL*16; it += 256) {
    const int l = it >> 4, c = it & 15;
    float4 o = {0.f,0.f,0.f,0.f};
#pragma unroll
    for (int s2 = 0; s2 < LL; ++s2) {
      const float p = ps[l][s2];
      const float4 vv = *(const float4*)&vs[s2][c*4];
      o.x += p*vv.x; o.y += p*vv.y; o.z += p*vv.z; o.w += p*vv.w;
    }
    ushort4 ov;
    ov.x = f2b(o.x); ov.y = f2b(o.y); ov.z = f2b(o.z); ov.w = f2b(o.w);
    *(ushort4*)(qg + l*1536 + c*4) = ov;
  }
}

// ============ attention, single query row l=19 (last layer) ============
__global__ __launch_bounds__(64) void attn19_kernel(
    const unsigned short* __restrict__ kvb, const unsigned short* __restrict__ q19,
    unsigned short* __restrict__ o19,
    const float* __restrict__ tau, const float* __restrict__ delta)
{
  const int bh = blockIdx.x;
  const int b = bh >> 3, h = bh & 7;
  __shared__ float ks[LL][DHD], vs[LL][DHD];
  const unsigned short* kg = kvb + (size_t)b * LL * 1024 + h * DHD;
  const unsigned short* vg = kg + 512;
  for (int it = threadIdx.x; it < LL*16; it += 64) {
    const int l = it >> 4, c = it & 15;
    const ushort4 kv = *(const ushort4*)(kg + l*1024 + c*4);
    const ushort4 vv = *(const ushort4*)(vg + l*1024 + c*4);
    ks[l][c*4+0]=b2f(kv.x); ks[l][c*4+1]=b2f(kv.y); ks[l][c*4+2]=b2f(kv.z); ks[l][c*4+3]=b2f(kv.w);
    vs[l][c*4+0]=b2f(vv.x); vs[l][c*4+1]=b2f(vv.y); vs[l][c*4+2]=b2f(vv.z); vs[l][c*4+3]=b2f(vv.w);
  }
  __syncthreads();
  const int e = threadIdx.x;
  const float q = b2f(q19[(size_t)b*DD + h*DHD + e]);
  const float ta = tau[b];
  float p[LL];
  float m = -1e30f;
#pragma unroll
  for (int s2 = 0; s2 < LL; ++s2){
    float d = q * ks[s2][e];
    d = wsum(d);
    p[s2] = 0.125f * (d * ta + delta[b*FE + s2]);
    m = fmaxf(m, p[s2]);
  }
  float sum = 0.f;
#pragma unroll
  for (int s2 = 0; s2 < LL; ++s2){ p[s2] = expf(p[s2]-m); sum += p[s2]; }
  const float r = 1.f / sum;
  float o = 0.f;
#pragma unroll
  for (int s2 = 0; s2 < LL; ++s2) o += p[s2] * vs[s2][e];
  o19[(size_t)b*DD + h*DHD + e] = f2b(o * r);
}

// ============ LayerNorm rows of 512, bf16 in-place (fp32 stats) ============
__global__ __launch_bounds__(256) void ln_bf16_kernel(
    unsigned short* __restrict__ x, const float* __restrict__ g, const float* __restrict__ be)
{
  const int row = (blockIdx.x << 2) + (threadIdx.x >> 6);
  const int lane = threadIdx.x & 63;
  const int d0 = lane * 8;
  unsigned short* xr = x + (size_t)row * DD + d0;
  const ushort4 a = *(const ushort4*)xr;
  const ushort4 b = *(const ushort4*)(xr + 4);
  float v[8];
  v[0]=b2f(a.x); v[1]=b2f(a.y); v[2]=b2f(a.z); v[3]=b2f(a.w);
  v[4]=b2f(b.x); v[5]=b2f(b.y); v[6]=b2f(b.z); v[7]=b2f(b.w);
  float s = v[0]+v[1]+v[2]+v[3]+v[4]+v[5]+v[6]+v[7];
  s = wsum(s);
  const float mu = s * (1.f/DD);
  float q = 0.f;
#pragma unroll
  for (int j = 0; j < 8; ++j){ float d = v[j]-mu; q += d*d; }
  q = wsum(q);
  const float rcp = rsqrtf(q*(1.f/DD) + 1e-5f);
  const float4 g0 = *(const float4*)(g + d0), g1 = *(const float4*)(g + d0 + 4);
  const float4 b0 = *(const float4*)(be + d0), b1 = *(const float4*)(be + d0 + 4);
  ushort4 u0, u1;
  u0.x = f2b((v[0]-mu)*rcp*g0.x + b0.x); u0.y = f2b((v[1]-mu)*rcp*g0.y + b0.y);
  u0.z = f2b((v[2]-mu)*rcp*g0.z + b0.z); u0.w = f2b((v[3]-mu)*rcp*g0.w + b0.w);
  u1.x = f2b((v[4]-mu)*rcp*g1.x + b1.x); u1.y = f2b((v[5]-mu)*rcp*g1.y + b1.y);
  u1.z = f2b((v[6]-mu)*rcp*g1.z + b1.z); u1.w = f2b((v[7]-mu)*rcp*g1.w + b1.w);
  *(ushort4*)xr = u0; *(ushort4*)(xr + 4) = u1;
}

// final: LN(x19b row b, bf16 in) -> W_pre -> denorm -> W_dec
__global__ __launch_bounds__(64) void final_kernel(
    const unsigned short* __restrict__ x19,
    const float* __restrict__ g, const float* __restrict__ be,
    const float* __restrict__ W_pre, const float* __restrict__ b_pre,
    const float* __restrict__ mean, const float* __restrict__ stdv,
    const float* __restrict__ W_dec, const float* __restrict__ b_dec,
    float* __restrict__ out)
{
  const int b = blockIdx.x;
  const int lane = threadIdx.x;
  const unsigned short* xr = x19 + (size_t)b * DD;
  float vals[8];
  float s = 0.f;
#pragma unroll
  for (int j = 0; j < 8; ++j){ vals[j] = b2f(xr[lane + j*64]); s += vals[j]; }
  s = wsum(s);
  const float mu = s * (1.f/DD);
  float vs = 0.f;
#pragma unroll
  for (int j = 0; j < 8; ++j){ float d = vals[j]-mu; vs += d*d; }
  vs = wsum(vs);
  const float rs = rsqrtf(vs*(1.f/DD) + 1e-5f);
#pragma unroll
  for (int j = 0; j < 8; ++j){ int d0 = lane + j*64; vals[j] = (vals[j]-mu)*rs*g[d0] + be[d0]; }
  float accb = 0.f;
  for (int f = 0; f < FE; ++f){
    float d = 0.f;
#pragma unroll
    for (int j = 0; j < 8; ++j){ int d0 = lane + j*64; d += vals[j]*W_pre[f*DD + d0]; }
    d = wsum(d);
    float o = (d + b_pre[f]) * stdv[b*FE + f] + mean[b*FE + f];
    accb += o * W_dec[f];
  }
  if (lane == 0) out[b] = accb + b_dec[0];
}

extern "C" void kernel_launch(void* const* d_in, const int* in_sizes, int n_in,
                              void* d_out, int out_size, void* d_ws, size_t ws_size,
                              hipStream_t stream) {
  const float* src     = (const float*)d_in[0];
  const float* W_feat  = (const float*)d_in[1];
  const float* b_feat  = (const float*)d_in[2];
  const float* tau_conv= (const float*)d_in[3];
  const float* tau_W0  = (const float*)d_in[4];
  const float* tau_b0  = (const float*)d_in[5];
  const float* tau_W1  = (const float*)d_in[6];
  const float* tau_b1  = (const float*)d_in[7];
  const float* tau_W2  = (const float*)d_in[8];
  const float* del_conv= (const float*)d_in[9];
  const float* del_W0  = (const float*)d_in[10];
  const float* del_b0  = (const float*)d_in[11];
  const float* del_W1  = (const float*)d_in[12];
  const float* del_b1  = (const float*)d_in[13];
  const float* del_W2  = (const float*)d_in[14];
  const float* Wq = (const float*)d_in[15]; const float* bq = (const float*)d_in[16];
  const float* Wk = (const float*)d_in[17]; const float* bk = (const float*)d_in[18];
  const float* Wv = (const float*)d_in[19]; const float* bv = (const float*)d_in[20];
  const float* Wo = (const float*)d_in[21]; const float* bo = (const float*)d_in[22];
  const float* Wc1= (const float*)d_in[23]; const float* bc1= (const float*)d_in[24];
  const float* Wc2= (const float*)d_in[25]; const float* bc2= (const float*)d_in[26];
  const float* ln1_g=(const float*)d_in[27]; const float* ln1_b=(const float*)d_in[28];
  const float* ln2_g=(const float*)d_in[29]; const float* ln2_b=(const float*)d_in[30];
  const float* lnf_g=(const float*)d_in[31]; const float* lnf_b=(const float*)d_in[32];
  const float* W_pre=(const float*)d_in[33]; const float* b_pre=(const float*)d_in[34];
  const float* W_dec=(const float*)d_in[35]; const float* b_dec=(const float*)d_in[36];
  float* out = (float*)d_out;

  // workspace plan: per-seq = 5120 (xb) + 20480 (union).
  auto need_floats = [](size_t cb)->size_t{
    size_t fl = 10240 + 2*(size_t)BB*FE;   // pe + stats
    fl += 4718592 + 4608;                  // bf16 weights + bqkv
    fl += 2*(size_t)BB*40;                 // z_tau, z_del
    fl += 2*(size_t)BB*DD;                 // h_a, h_b
    fl += BB + (size_t)BB*FE;              // taub, delta
    fl += cb*25600;                        // xb + union
    fl += 64*64;
    return fl;
  };
  size_t maxCB = BB;
  while (maxCB > 64 && need_floats(maxCB)*4 > ws_size) maxCB -= 64;
  size_t nch = (BB + maxCB - 1) / maxCB;
  size_t CB = ((BB + nch - 1) / nch + 63) & ~(size_t)63;
  if (CB > maxCB) CB = maxCB;

  float* w = (float*)d_ws;
  size_t off = 0;
  auto take = [&](size_t n){ float* p = w + off; off += (n + 63) & ~(size_t)63; return p; };
  float* pe    = take(LL*DD);
  float* meanG = take((size_t)BB*FE);
  float* stdvG = take((size_t)BB*FE);
  unsigned short* Wqkvb = (unsigned short*)take((size_t)NLAY*1536*DD/2);
  unsigned short* Wob   = (unsigned short*)take((size_t)NLAY*DD*DD/2);
  unsigned short* Wc1b  = (unsigned short*)take((size_t)NLAY*FFD*DD/2);
  unsigned short* Wc2b  = (unsigned short*)take((size_t)NLAY*DD*FFD/2);
  float* bqkv  = take(NLAY*1536);
  float* z_tau = take((size_t)BB*40);
  float* z_del = take((size_t)BB*40);
  float* h_a   = take((size_t)BB*DD);
  float* h_b   = take((size_t)BB*DD);
  float* taubG = take(BB);
  float* deltaG= take((size_t)BB*FE);
  unsigned short* xb = (unsigned short*)take(CB*LL*DD/2);
  float* unionBuf = take(CB*20480);
  float* sbuf = unionBuf;                                           // [cb,400] fp32
  unsigned short* qkvb = (unsigned short*)unionBuf;                 // [cm,1536] bf16
  unsigned short* hb   = (unsigned short*)unionBuf;                 // [cm,2048] bf16
  unsigned short* kvb  = (unsigned short*)unionBuf;                 // [cm,1024] bf16
  unsigned short* q19b = (unsigned short*)(unionBuf + CB*10240);    // [cb,512] bf16
  unsigned short* o19b = (unsigned short*)(unionBuf + CB*10496);    // [cb,512] bf16
  unsigned short* hb19 = (unsigned short*)(unionBuf + CB*10752);    // [cb,2048] bf16
  unsigned short* x19b = (unsigned short*)(unionBuf + CB*11776);    // [cb,512] bf16

  // ---- whole-batch prep ----
  pe_kernel<<<20, 256, 0, stream>>>(pe);
  stats_kernel<<<(BB*FE + 255)/256, 256, 0, stream>>>(src, meanG, stdvG, BB*FE);
  {
    const int nqkv = DD*DD;
    for (int l = 0; l < NLAY; ++l) {
      cvt_bf16_kernel<<<(nqkv+255)/256, 256, 0, stream>>>(Wq + (size_t)l*nqkv, Wqkvb + (size_t)l*1536*DD, nqkv);
      cvt_bf16_kernel<<<(nqkv+255)/256, 256, 0, stream>>>(Wk + (size_t)l*nqkv, Wqkvb + (size_t)l*1536*DD + (size_t)512*DD, nqkv);
      cvt_bf16_kernel<<<(nqkv+255)/256, 256, 0, stream>>>(Wv + (size_t)l*nqkv, Wqkvb + (size_t)l*1536*DD + (size_t)1024*DD, nqkv);
    }
    int n1 = NLAY*DD*DD, n2 = NLAY*FFD*DD;
    cvt_bf16_kernel<<<(n1+255)/256, 256, 0, stream>>>(Wo, Wob, n1);
    cvt_bf16_kernel<<<(n2+255)/256, 256, 0, stream>>>(Wc1, Wc1b, n2);
    cvt_bf16_kernel<<<(n2+255)/256, 256, 0, stream>>>(Wc2, Wc2b, n2);
    concat_bias_kernel<<<(NLAY*1536+255)/256, 256, 0, stream>>>(bq, bk, bv, bqkv);
  }
  {
    const dim3 gP(8, BB/64);
    convz_kernel<<<BB, 64, 0, stream>>>(src, tau_conv, del_conv, meanG, stdvG, z_tau, z_del);
    gemm_xwt<true,true,false><<<gP, 256, 0, stream>>>(z_tau,40, tau_W0,40, tau_b0, h_a,DD, BB,DD,40, nullptr,nullptr);
    gemm_xwt<true,true,false><<<gP, 256, 0, stream>>>(h_a,DD, tau_W1,DD, tau_b1, h_b,DD, BB,DD,DD, nullptr,nullptr);
    tau_head<<<BB/4, 256, 0, stream>>>(h_b, tau_W2, taubG);
    gemm_xwt<true,true,false><<<gP, 256, 0, stream>>>(z_del,40, del_W0,40, del_b0, h_a,DD, BB,DD,40, nullptr,nullptr);
    gemm_xwt<true,true,false><<<gP, 256, 0, stream>>>(h_a,DD, del_W1,DD, del_b1, h_b,DD, BB,DD,DD, nullptr,nullptr);
    delta_head<<<BB, 256, 0, stream>>>(h_b, del_W2, deltaG);
  }

  const int iL = NLAY - 1;

  for (size_t b0 = 0; b0 < BB; b0 += CB) {
    const size_t cb = (BB - b0 < CB) ? (BB - b0) : CB;   // multiple of 64
    const int cm = (int)(cb * LL);                        // multiple of 1280
    const float* srcC  = src + b0*LL*FE;
    const float* meanC = meanG + b0*FE;
    const float* stdvC = stdvG + b0*FE;
    const float* taub  = taubG + b0;
    const float* delta = deltaG + b0*FE;

    const dim3 gEmb(8, cm/64);
    const dim3 gQKV(1536/128, cm/128);
    const dim3 gD(DD/128, cm/128);
    const dim3 gF1(FFD/128, cm/128);
    const dim3 gKV(1024/128, cm/128);
    const dim3 g19D(DD/128, (int)cb/64);
    const dim3 g19F(FFD/128, (int)cb/64);

    snorm_kernel<<<(int)((cb*LL*FE + 255)/256), 256, 0, stream>>>(srcC, meanC, stdvC, sbuf, (int)(cb*LL*FE));
    // embedding: xb = bf16(s @ W_feat^T + b_feat + pe)
    gemm_xwt<false,true,true><<<gEmb, 256, 0, stream>>>(sbuf,FE, W_feat,FE, b_feat, nullptr,DD, cm,DD,FE, pe, xb);

    // layers 0..NLAY-2 (full width)
    for (int i = 0; i < iL; ++i) {
      const size_t wOfs = (size_t)i * DD * DD;
      const size_t fOfs = (size_t)i * FFD * DD;
      bgemm<false,true,false><<<gQKV, 256, 0, stream>>>(xb,DD, Wqkvb + (size_t)i*1536*DD,DD, bqkv + i*1536, nullptr,0, qkvb,1536, DD);
      attn_kernel<<<(int)cb*HH, 256, 0, stream>>>(qkvb, taub, delta);
      // O-proj: xb = bf16(o @ Wo^T + bo + xb)  (o = qkvb cols 0..511)
      bgemm<false,true,true><<<gD, 256, 0, stream>>>(qkvb,1536, Wob+wOfs,DD, bo+i*DD, xb,DD, xb,DD, DD);
      ln_bf16_kernel<<<cm/4, 256, 0, stream>>>(xb, ln1_g+i*DD, ln1_b+i*DD);
      // FFN1: hb = relu(xb @ Wc1^T + bc1)  [cm,2048]
      bgemm<true,true,false><<<gF1, 256, 0, stream>>>(xb,DD, Wc1b+fOfs,DD, bc1+i*FFD, nullptr,0, hb,FFD, DD);
      // FFN2: xb = bf16(hb @ Wc2^T + bc2 + xb), K=2048
      bgemm<false,true,true><<<gD, 256, 0, stream>>>(hb,FFD, Wc2b+fOfs,FFD, bc2+i*DD, xb,DD, xb,DD, FFD);
      ln_bf16_kernel<<<cm/4, 256, 0, stream>>>(xb, ln2_g+i*DD, ln2_b+i*DD);
    }

    // last layer: only row l=19 feeds the output
    {
      const size_t wOfs = (size_t)iL * DD * DD;
      const size_t fOfs = (size_t)iL * FFD * DD;
      bgemm<false,true,false><<<gKV, 256, 0, stream>>>(xb,DD, Wqkvb + (size_t)iL*1536*DD + (size_t)512*DD,DD, bqkv + iL*1536 + 512, nullptr,0, kvb,1024, DD);
      bgemm64<false,true,false><<<g19D, 256, 0, stream>>>(xb + 19*DD, LL*DD, Wqkvb + (size_t)iL*1536*DD,DD, bqkv + iL*1536, nullptr,0, q19b,DD, DD);
      attn19_kernel<<<(int)cb*HH, 64, 0, stream>>>(kvb, q19b, o19b, taub, delta);
      bgemm64<false,true,true><<<g19D, 256, 0, stream>>>(o19b,DD, Wob+wOfs,DD, bo+iL*DD, xb + 19*DD, LL*DD, x19b,DD, DD);
      ln_bf16_kernel<<<(int)cb/4, 256, 0, stream>>>(x19b, ln1_g+iL*DD, ln1_b+iL*DD);
      bgemm64<true,true,false><<<g19F, 256, 0, stream>>>(x19b,DD, Wc1b+fOfs,DD, bc1+iL*FFD, nullptr,0, hb19,FFD, DD);
      bgemm64<false,true,true><<<g19D, 256, 0, stream>>>(hb19,FFD, Wc2b+fOfs,FFD, bc2+iL*DD, x19b,DD, x19b,DD, FFD);
      ln_bf16_kernel<<<(int)cb/4, 256, 0, stream>>>(x19b, ln2_g+iL*DD, ln2_b+iL*DD);
    }

    final_kernel<<<(int)cb, 64, 0, stream>>>(x19b, lnf_g, lnf_b, W_pre, b_pre, meanC, stdvC, W_dec, b_dec, out + b0);
  }
}

// Round 14
// 2546.762 us; speedup vs baseline: 1.0290x; 1.0290x over previous
//
#include <hip/hip_runtime.h>
#include <math.h>
#include <stdint.h>

// NSTransformer forward. bf16-MFMA GEMMs: 128x128 tile, 3-buffer LDS pipeline,
// counted vmcnt(4) (never 0), ONE barrier per K-step (end barrier proven
// redundant), bf16 residual stream, fused QKV, row-19 last layer, XCD swizzle.
#define BB 4096
#define LL 20
#define FE 20
#define DD 512
#define HH 8
#define DHD 64
#define FFD 2048
#define NLAY 3

typedef __bf16 bf16x8 __attribute__((ext_vector_type(8)));
typedef float f32x4 __attribute__((ext_vector_type(4)));

// Direct C-style casts (addrspacecast) — NOT via uintptr_t (round-3 abort cause).
__device__ __forceinline__ void gload_lds16(const unsigned short* g, unsigned short* l){
  __builtin_amdgcn_global_load_lds(
      (const __attribute__((address_space(1))) void*)g,
      (__attribute__((address_space(3))) void*)l, 16, 0, 0);
}

__device__ __forceinline__ float wsum(float v){
#pragma unroll
  for (int o = 32; o > 0; o >>= 1) v += __shfl_xor(v, o, 64);
  return v;
}

__device__ __forceinline__ unsigned short f2b(float f){
  unsigned u = __float_as_uint(f);
  u += 0x7FFFu + ((u >> 16) & 1u);
  return (unsigned short)(u >> 16);
}
__device__ __forceinline__ float b2f(unsigned short b){
  return __uint_as_float(((unsigned)b) << 16);
}

// XCD-aware bijective block swizzle (m204).
__device__ __forceinline__ int2 xcd_swz(){
  const int nx = gridDim.x;
  const int nwg = nx * gridDim.y;
  const int orig = blockIdx.y * nx + blockIdx.x;
  const int q = nwg >> 3, r = nwg & 7;
  const int xcd = orig & 7, idx = orig >> 3;
  const int wg = (xcd < r ? xcd*(q+1) : r*(q+1) + (xcd-r)*q) + idx;
  return make_int2(wg % nx, wg / nx);
}

// ============ bf16 MFMA GEMM, 128x128 tile, 3-buffer counted-vmcnt, 1 barrier/iter ===
// Invariant at iter start: outstanding = stage(t), stage(t+1) (8 loads).
// vmcnt(4) retires stage(t) per-wave (in-order retirement, m135); barrier makes
// it collective. stage(t+1) stays in flight ACROSS the barrier (T4 property).
// Single barrier is sufficient: a wave stages buffer (t+3)%3 = t%3 only after
// the start barrier of iter t+1, which all waves reach only after completing
// their iter-t reads of buffer t%3. Tail: clamped re-stage into dead buffer.
// LDS 48 KB -> 3 blocks/CU. Requires nt >= 2 (all uses have K >= 512).
template<bool RELU, bool BIAS, bool RES>
__global__ __launch_bounds__(256) void bgemm(
    const unsigned short* __restrict__ A, int lda,
    const unsigned short* __restrict__ W, int ldw,
    const float* __restrict__ bias,
    const unsigned short* res, int ldr,
    unsigned short* __restrict__ Cout, int ldc, int K)
{
  __shared__ __align__(16) unsigned short Asm[3][128*32];
  __shared__ __align__(16) unsigned short Bsm[3][128*32];
  const int2 swz = xcd_swz();
  const int bn = swz.x << 7, bm = swz.y << 7;
  const int tid = threadIdx.x;
  const int wave = tid >> 6, lane = tid & 63;
  const int wr = wave >> 1, wc = wave & 1;
  const int sr = lane >> 2, slot = lane & 3;
  const int rg = lane & 15, cg = lane >> 4;

  f32x4 acc[4][4];
#pragma unroll
  for (int i = 0; i < 4; ++i)
#pragma unroll
    for (int j = 0; j < 4; ++j) acc[i][j] = (f32x4){0.f,0.f,0.f,0.f};

  auto stage = [&](int kt, int b){
    const int k0 = kt << 5;
#pragma unroll
    for (int i = 0; i < 2; ++i) {
      const int r  = (i<<6) + (wave<<4) + sr;
      const int ch = slot ^ ((r>>1)&3);
      gload_lds16(A + (size_t)(bm + r)*lda + k0 + (ch<<3),
                  &Asm[b][((i<<6) + (wave<<4))*32]);
    }
#pragma unroll
    for (int i = 0; i < 2; ++i) {
      const int r  = (i<<6) + (wave<<4) + sr;
      const int ch = slot ^ ((r>>1)&3);
      gload_lds16(W + (size_t)(bn + r)*ldw + k0 + (ch<<3),
                  &Bsm[b][((i<<6) + (wave<<4))*32]);
    }
  };

  const int nt = K >> 5;
  // prologue: stage K-tiles 0,1 into buffers 0,1 (8 loads outstanding)
  stage(0, 0);
  stage(1, 1);

  int cur = 0;            // buffer for tile t
  int nxt2 = 2;           // buffer for tile t+2
  for (int t = 0; t < nt; ++t){
    // per-wave: stage(t) landed (<=4 outstanding = stage t+1); then collective.
    asm volatile("s_waitcnt vmcnt(4)" ::: "memory");
    __builtin_amdgcn_s_barrier();
    __builtin_amdgcn_sched_barrier(0);
    asm volatile("" ::: "memory");

    const int ts = (t + 2 < nt) ? t + 2 : nt - 1;   // clamped tail re-stage

    bf16x8 af[4], bfr[4];
#pragma unroll
    for (int mi = 0; mi < 4; ++mi){
      int r = (wr<<6) + (mi<<4) + rg;
      af[mi] = *(const bf16x8*)&Asm[cur][r*32 + ((cg ^ ((r>>1)&3))<<3)];
    }
#pragma unroll
    for (int ni = 0; ni < 4; ++ni){
      int r = (wc<<6) + (ni<<4) + rg;
      bfr[ni] = *(const bf16x8*)&Bsm[cur][r*32 + ((cg ^ ((r>>1)&3))<<3)];
    }
    // issue next stage; lands >= 2 iterations later (safe: buffer dead)
    stage(ts, nxt2);

    __builtin_amdgcn_s_setprio(1);
#pragma unroll
    for (int mi = 0; mi < 4; ++mi)
#pragma unroll
      for (int ni = 0; ni < 4; ++ni)
        acc[mi][ni] = __builtin_amdgcn_mfma_f32_16x16x32_bf16(af[mi], bfr[ni], acc[mi][ni], 0, 0, 0);
    __builtin_amdgcn_s_setprio(0);

    cur = (cur == 2) ? 0 : cur + 1;
    nxt2 = (nxt2 == 2) ? 0 : nxt2 + 1;
  }

#pragma unroll
  for (int mi = 0; mi < 4; ++mi){
#pragma unroll
    for (int ni = 0; ni < 4; ++ni){
      const int row0 = bm + (wr<<6) + (mi<<4) + (cg<<2);
      const int col  = bn + (wc<<6) + (ni<<4) + rg;
      float bv = BIAS ? bias[col] : 0.f;
#pragma unroll
      for (int j = 0; j < 4; ++j){
        float v = acc[mi][ni][j] + bv;
        if (RES)  v += b2f(res[(size_t)(row0+j)*ldr + col]);
        if (RELU) v = fmaxf(v, 0.f);
        Cout[(size_t)(row0+j)*ldc + col] = f2b(v);
      }
    }
  }
}

// ============ bf16 MFMA GEMM, 64x128 tile (row-19 tail; proven 2-phase) ============
template<bool RELU, bool BIAS, bool RES>
__global__ __launch_bounds__(256) void bgemm64(
    const unsigned short* __restrict__ A, int lda,
    const unsigned short* __restrict__ W, int ldw,
    const float* __restrict__ bias,
    const unsigned short* res, int ldr,
    unsigned short* __restrict__ Cout, int ldc, int K)
{
  __shared__ __align__(16) unsigned short Asm[2][64*32];
  __shared__ __align__(16) unsigned short Bsm[2][128*32];
  const int2 swz = xcd_swz();
  const int bn = swz.x << 7, bm = swz.y << 6;
  const int tid = threadIdx.x;
  const int wave = tid >> 6, lane = tid & 63;
  const int sr = lane >> 2, slot = lane & 3;
  const int rg = lane & 15, cg = lane >> 4;

  f32x4 acc[4][2];
#pragma unroll
  for (int i = 0; i < 4; ++i)
#pragma unroll
    for (int j = 0; j < 2; ++j) acc[i][j] = (f32x4){0.f,0.f,0.f,0.f};

  auto stage = [&](int kt, int b){
    const int k0 = kt << 5;
    {
      const int r  = (wave<<4) + sr;
      const int ch = slot ^ ((r>>1)&3);
      gload_lds16(A + (size_t)(bm + r)*lda + k0 + (ch<<3),
                  &Asm[b][(wave<<4)*32]);
    }
#pragma unroll
    for (int i = 0; i < 2; ++i) {
      const int r  = (i<<6) + (wave<<4) + sr;
      const int ch = slot ^ ((r>>1)&3);
      gload_lds16(W + (size_t)(bn + r)*ldw + k0 + (ch<<3),
                  &Bsm[b][((i<<6) + (wave<<4))*32]);
    }
  };

  auto compute = [&](int b){
    bf16x8 af[4], bfr[2];
#pragma unroll
    for (int mi = 0; mi < 4; ++mi){
      int r = (mi<<4) + rg;
      af[mi] = *(const bf16x8*)&Asm[b][r*32 + ((cg ^ ((r>>1)&3))<<3)];
    }
#pragma unroll
    for (int ni = 0; ni < 2; ++ni){
      int r = (wave<<5) + (ni<<4) + rg;
      bfr[ni] = *(const bf16x8*)&Bsm[b][r*32 + ((cg ^ ((r>>1)&3))<<3)];
    }
#pragma unroll
    for (int mi = 0; mi < 4; ++mi)
#pragma unroll
      for (int ni = 0; ni < 2; ++ni)
        acc[mi][ni] = __builtin_amdgcn_mfma_f32_16x16x32_bf16(af[mi], bfr[ni], acc[mi][ni], 0, 0, 0);
  };

  const int nt = K >> 5;
  stage(0, 0);
  __syncthreads();
  int cur = 0;
  for (int t = 0; t < nt; ++t){
    if (t + 1 < nt) stage(t + 1, cur ^ 1);
    compute(cur);
    __syncthreads();
    cur ^= 1;
  }

#pragma unroll
  for (int mi = 0; mi < 4; ++mi){
#pragma unroll
    for (int ni = 0; ni < 2; ++ni){
      const int row0 = bm + (mi<<4) + (cg<<2);
      const int col  = bn + (wave<<5) + (ni<<4) + rg;
      float bv = BIAS ? bias[col] : 0.f;
#pragma unroll
      for (int j = 0; j < 4; ++j){
        float v = acc[mi][ni][j] + bv;
        if (RES)  v += b2f(res[(size_t)(row0+j)*ldr + col]);
        if (RELU) v = fmaxf(v, 0.f);
        Cout[(size_t)(row0+j)*ldc + col] = f2b(v);
      }
    }
  }
}

// ============ fp32 tiled GEMM (projector fp32 out; embed PE -> bf16-only out) ============
template<bool RELU, bool BIAS, bool PE>
__global__ __launch_bounds__(256) void gemm_xwt(
    const float* __restrict__ A, int lda,
    const float* __restrict__ W, int ldw,
    const float* __restrict__ bias,
    float* __restrict__ C, int ldc,
    int M, int N, int K,
    const float* __restrict__ pe, unsigned short* __restrict__ xbout)
{
  __shared__ float As[16][72];
  __shared__ float Ws[16][72];
  const int bm = blockIdx.y << 6, bn = blockIdx.x << 6;
  const int tid = threadIdx.x;
  const int tx = tid & 15, ty = tid >> 4;
  const int lr = tid >> 2;
  const int lc = (tid & 3) << 2;
  float acc[4][4] = {{0.f}};
  const float* Ap = A + (size_t)(bm + lr) * lda;
  const float* Wp = W + (size_t)(bn + lr) * ldw;
  for (int k0 = 0; k0 < K; k0 += 16) {
    float4 av, wv;
    if (k0 + 16 <= K) {
      av = *(const float4*)(Ap + k0 + lc);
      wv = *(const float4*)(Wp + k0 + lc);
    } else {
      float aa[4] = {0,0,0,0}, ww[4] = {0,0,0,0};
#pragma unroll
      for (int j = 0; j < 4; ++j){ int kk = k0 + lc + j; if (kk < K){ aa[j] = Ap[kk]; ww[j] = Wp[kk]; } }
      av = make_float4(aa[0],aa[1],aa[2],aa[3]);
      wv = make_float4(ww[0],ww[1],ww[2],ww[3]);
    }
    As[lc+0][lr]=av.x; As[lc+1][lr]=av.y; As[lc+2][lr]=av.z; As[lc+3][lr]=av.w;
    Ws[lc+0][lr]=wv.x; Ws[lc+1][lr]=wv.y; Ws[lc+2][lr]=wv.z; Ws[lc+3][lr]=wv.w;
    __syncthreads();
#pragma unroll
    for (int k = 0; k < 16; ++k) {
      const float4 a = *(const float4*)(&As[k][ty<<2]);
      const float4 b = *(const float4*)(&Ws[k][tx<<2]);
      acc[0][0]+=a.x*b.x; acc[0][1]+=a.x*b.y; acc[0][2]+=a.x*b.z; acc[0][3]+=a.x*b.w;
      acc[1][0]+=a.y*b.x; acc[1][1]+=a.y*b.y; acc[1][2]+=a.y*b.z; acc[1][3]+=a.y*b.w;
      acc[2][0]+=a.z*b.x; acc[2][1]+=a.z*b.y; acc[2][2]+=a.z*b.z; acc[2][3]+=a.z*b.w;
      acc[3][0]+=a.w*b.x; acc[3][1]+=a.w*b.y; acc[3][2]+=a.w*b.z; acc[3][3]+=a.w*b.w;
    }
    __syncthreads();
  }
#pragma unroll
  for (int i = 0; i < 4; ++i) {
    const int m = bm + (ty<<2) + i;
#pragma unroll
    for (int j = 0; j < 4; ++j) {
      const int col = bn + (tx<<2) + j;
      float v = acc[i][j];
      if (BIAS) v += bias[col];
      if (PE)   v += pe[(m % LL)*DD + col];
      if (RELU) v = fmaxf(v, 0.f);
      if (PE) xbout[(size_t)m*ldc + col] = f2b(v);
      else    C[(size_t)m*ldc + col] = v;
    }
  }
}

// ============ misc small kernels ============
__global__ void cvt_bf16_kernel(const float* __restrict__ in, unsigned short* __restrict__ out, int n){
  int i = blockIdx.x * 256 + threadIdx.x;
  if (i < n) out[i] = f2b(in[i]);
}

__global__ void concat_bias_kernel(const float* __restrict__ bq, const float* __restrict__ bk,
                                   const float* __restrict__ bv, float* __restrict__ bqkv){
  int i = blockIdx.x * 256 + threadIdx.x;
  if (i >= NLAY*1536) return;
  int l = i / 1536, r = i % 1536;
  int s = r >> 9, j = r & 511;
  const float* srcp = (s == 0) ? bq : (s == 1) ? bk : bv;
  bqkv[i] = srcp[l*DD + j];
}

__global__ void pe_kernel(float* __restrict__ pe){
  int i = blockIdx.x * 256 + threadIdx.x;
  int l = i >> 8, hd = i & 255;
  float dv = expf((2.f * hd) * (-9.210340371976184f / 512.f));
  float a = (float)l * dv;
  pe[l*DD + 2*hd]     = sinf(a);
  pe[l*DD + 2*hd + 1] = cosf(a);
}

__global__ void stats_kernel(const float* __restrict__ src, float* __restrict__ mean,
                             float* __restrict__ stdv, int nbf){
  int i = blockIdx.x * 256 + threadIdx.x;
  if (i >= nbf) return;
  int b = i / FE, f = i % FE;
  const float* p = src + (size_t)b * (LL*FE) + f;
  float v[LL]; float s = 0.f;
#pragma unroll
  for (int l = 0; l < LL; ++l){ v[l] = p[l*FE]; s += v[l]; }
  float m = s * (1.f/LL);
  float q = 0.f;
#pragma unroll
  for (int l = 0; l < LL; ++l){ float d = v[l]-m; q += d*d; }
  mean[i] = m;
  stdv[i] = sqrtf(q * (1.f/LL) + 1e-5f);
}

__global__ void snorm_kernel(const float* __restrict__ src, const float* __restrict__ mean,
                             const float* __restrict__ stdv, float* __restrict__ s, int n){
  int i = blockIdx.x * 256 + threadIdx.x;
  if (i >= n) return;
  int b = i / (LL*FE);
  int f = i % FE;
  int bf = b*FE + f;
  s[i] = (src[i] - mean[bf]) / stdv[bf];
}

__global__ __launch_bounds__(64) void convz_kernel(
    const float* __restrict__ src, const float* __restrict__ wt, const float* __restrict__ wd,
    const float* __restrict__ mean, const float* __restrict__ stdv,
    float* __restrict__ z_tau, float* __restrict__ z_del)
{
  int b = blockIdx.x;
  __shared__ float ss[LL*FE];
  __shared__ float wct[LL*3], wcd[LL*3];
  for (int idx = threadIdx.x; idx < LL*FE; idx += 64) ss[idx] = src[(size_t)b*LL*FE + idx];
  if (threadIdx.x < 60){ wct[threadIdx.x] = wt[threadIdx.x]; wcd[threadIdx.x] = wd[threadIdx.x]; }
  __syncthreads();
  if (threadIdx.x < 40) {
    int f = threadIdx.x % FE;
    bool isdel = threadIdx.x >= FE;
    const float* w = isdel ? wcd : wct;
    int fm = (f + FE - 1) % FE, fp = (f + 1) % FE;
    float acc = 0.f;
#pragma unroll
    for (int t = 0; t < LL; ++t){
      const float* r = ss + t*FE;
      acc += r[fm]*w[t*3+0] + r[f]*w[t*3+1] + r[fp]*w[t*3+2];
    }
    if (isdel){ z_del[b*40 + f] = acc; z_del[b*40 + 20 + f] = mean[b*FE + f]; }
    else      { z_tau[b*40 + f] = acc; z_tau[b*40 + 20 + f] = stdv[b*FE + f]; }
  }
}

__global__ __launch_bounds__(256) void tau_head(const float* __restrict__ h, const float* __restrict__ W2, float* __restrict__ tau){
  const int b = (blockIdx.x << 2) + (threadIdx.x >> 6);
  const int lane = threadIdx.x & 63;
  const float* hb = h + (size_t)b * DD;
  float s = 0.f;
#pragma unroll
  for (int j = 0; j < 8; ++j){ int d0 = lane + j*64; s += hb[d0]*W2[d0]; }
  s = wsum(s);
  if (lane == 0) tau[b] = expf(s);
}

__global__ __launch_bounds__(256) void delta_head(const float* __restrict__ h, const float* __restrict__ W2, float* __restrict__ delta){
  const int b = blockIdx.x;
  const int w = threadIdx.x >> 6, lane = threadIdx.x & 63;
  const float* hb = h + (size_t)b * DD;
  for (int f = w; f < FE; f += 4){
    float s = 0.f;
#pragma unroll
    for (int j = 0; j < 8; ++j){ int d0 = lane + j*64; s += hb[d0]*W2[(size_t)f*DD + d0]; }
    s = wsum(s);
    if (lane == 0) delta[b*FE + f] = s;
  }
}

// ============ attention (full, layers 0..NLAY-2); o IN PLACE over q ============
__global__ __launch_bounds__(256) void attn_kernel(
    unsigned short* __restrict__ qkv,
    const float* __restrict__ tau, const float* __restrict__ delta)
{
  const int bh = blockIdx.x;
  const int b = bh >> 3, h = bh & 7;
  __shared__ float qs[LL][68];
  __shared__ float kt[DHD][25];
  __shared__ float vs[LL][DHD];
  __shared__ float ps[LL][LL+1];
  const size_t base = (size_t)b * LL * 1536 + h * DHD;
  unsigned short* qg = qkv + base;
  const unsigned short* kg = qkv + base + 512;
  const unsigned short* vg = qkv + base + 1024;

  for (int it = threadIdx.x; it < LL*16; it += 256) {
    const int l = it >> 4, c = it & 15;
    const ushort4 qv = *(const ushort4*)(qg + l*1536 + c*4);
    const ushort4 kv = *(const ushort4*)(kg + l*1536 + c*4);
    const ushort4 vv = *(const ushort4*)(vg + l*1536 + c*4);
    qs[l][c*4+0]=b2f(qv.x); qs[l][c*4+1]=b2f(qv.y); qs[l][c*4+2]=b2f(qv.z); qs[l][c*4+3]=b2f(qv.w);
    kt[c*4+0][l]=b2f(kv.x); kt[c*4+1][l]=b2f(kv.y); kt[c*4+2][l]=b2f(kv.z); kt[c*4+3][l]=b2f(kv.w);
    vs[l][c*4+0]=b2f(vv.x); vs[l][c*4+1]=b2f(vv.y); vs[l][c*4+2]=b2f(vv.z); vs[l][c*4+3]=b2f(vv.w);
  }
  __syncthreads();

  const float ta = tau[b];
  for (int idx = threadIdx.x; idx < LL*LL; idx += 256) {
    const int l = idx / LL, s2 = idx % LL;
    float d = 0.f;
#pragma unroll
    for (int e = 0; e < DHD; ++e) d += qs[l][e]*kt[e][s2];
    ps[l][s2] = 0.125f * (d * ta + delta[b*FE + s2]);
  }
  __syncthreads();

  if (threadIdx.x < LL) {
    const int l = threadIdx.x;
    float m = -1e30f;
#pragma unroll
    for (int s2 = 0; s2 < LL; ++s2) m = fmaxf(m, ps[l][s2]);
    float sum = 0.f;
#pragma unroll
    for (int s2 = 0; s2 < LL; ++s2){ float e2 = expf(ps[l][s2]-m); ps[l][s2] = e2; sum += e2; }
    const float r = 1.f / sum;
#pragma unroll
    for (int s2 = 0; s2 < LL; ++s2) ps[l][s2] *= r;
  }
  __syncthreads();

  for (int it = threadIdx.x; it < LL*16; it += 256) {
    const int l = it >> 4, c = it & 15;
    float4 o = {0.f,0.f,0.f,0.f};
#pragma unroll
    for (int s2 = 0; s2 < LL; ++s2) {
      const float p = ps[l][s2];
      const float4 vv = *(const float4*)&vs[s2][c*4];
      o.x += p*vv.x; o.y += p*vv.y; o.z += p*vv.z; o.w += p*vv.w;
    }
    ushort4 ov;
    ov.x = f2b(o.x); ov.y = f2b(o.y); ov.z = f2b(o.z); ov.w = f2b(o.w);
    *(ushort4*)(qg + l*1536 + c*4) = ov;
  }
}

// ============ attention, single query row l=19 (last layer) ============
__global__ __launch_bounds__(64) void attn19_kernel(
    const unsigned short* __restrict__ kvb, const unsigned short* __restrict__ q19,
    unsigned short* __restrict__ o19,
    const float* __restrict__ tau, const float* __restrict__ delta)
{
  const int bh = blockIdx.x;
  const int b = bh >> 3, h = bh & 7;
  __shared__ float ks[LL][DHD], vs[LL][DHD];
  const unsigned short* kg = kvb + (size_t)b * LL * 1024 + h * DHD;
  const unsigned short* vg = kg + 512;
  for (int it = threadIdx.x; it < LL*16; it += 64) {
    const int l = it >> 4, c = it & 15;
    const ushort4 kv = *(const ushort4*)(kg + l*1024 + c*4);
    const ushort4 vv = *(const ushort4*)(vg + l*1024 + c*4);
    ks[l][c*4+0]=b2f(kv.x); ks[l][c*4+1]=b2f(kv.y); ks[l][c*4+2]=b2f(kv.z); ks[l][c*4+3]=b2f(kv.w);
    vs[l][c*4+0]=b2f(vv.x); vs[l][c*4+1]=b2f(vv.y); vs[l][c*4+2]=b2f(vv.z); vs[l][c*4+3]=b2f(vv.w);
  }
  __syncthreads();
  const int e = threadIdx.x;
  const float q = b2f(q19[(size_t)b*DD + h*DHD + e]);
  const float ta = tau[b];
  float p[LL];
  float m = -1e30f;
#pragma unroll
  for (int s2 = 0; s2 < LL; ++s2){
    float d = q * ks[s2][e];
    d = wsum(d);
    p[s2] = 0.125f * (d * ta + delta[b*FE + s2]);
    m = fmaxf(m, p[s2]);
  }
  float sum = 0.f;
#pragma unroll
  for (int s2 = 0; s2 < LL; ++s2){ p[s2] = expf(p[s2]-m); sum += p[s2]; }
  const float r = 1.f / sum;
  float o = 0.f;
#pragma unroll
  for (int s2 = 0; s2 < LL; ++s2) o += p[s2] * vs[s2][e];
  o19[(size_t)b*DD + h*DHD + e] = f2b(o * r);
}

// ============ LayerNorm rows of 512, bf16 in-place (fp32 stats) ============
__global__ __launch_bounds__(256) void ln_bf16_kernel(
    unsigned short* __restrict__ x, const float* __restrict__ g, const float* __restrict__ be)
{
  const int row = (blockIdx.x << 2) + (threadIdx.x >> 6);
  const int lane = threadIdx.x & 63;
  const int d0 = lane * 8;
  unsigned short* xr = x + (size_t)row * DD + d0;
  const ushort4 a = *(const ushort4*)xr;
  const ushort4 b = *(const ushort4*)(xr + 4);
  float v[8];
  v[0]=b2f(a.x); v[1]=b2f(a.y); v[2]=b2f(a.z); v[3]=b2f(a.w);
  v[4]=b2f(b.x); v[5]=b2f(b.y); v[6]=b2f(b.z); v[7]=b2f(b.w);
  float s = v[0]+v[1]+v[2]+v[3]+v[4]+v[5]+v[6]+v[7];
  s = wsum(s);
  const float mu = s * (1.f/DD);
  float q = 0.f;
#pragma unroll
  for (int j = 0; j < 8; ++j){ float d = v[j]-mu; q += d*d; }
  q = wsum(q);
  const float rcp = rsqrtf(q*(1.f/DD) + 1e-5f);
  const float4 g0 = *(const float4*)(g + d0), g1 = *(const float4*)(g + d0 + 4);
  const float4 b0 = *(const float4*)(be + d0), b1 = *(const float4*)(be + d0 + 4);
  ushort4 u0, u1;
  u0.x = f2b((v[0]-mu)*rcp*g0.x + b0.x); u0.y = f2b((v[1]-mu)*rcp*g0.y + b0.y);
  u0.z = f2b((v[2]-mu)*rcp*g0.z + b0.z); u0.w = f2b((v[3]-mu)*rcp*g0.w + b0.w);
  u1.x = f2b((v[4]-mu)*rcp*g1.x + b1.x); u1.y = f2b((v[5]-mu)*rcp*g1.y + b1.y);
  u1.z = f2b((v[6]-mu)*rcp*g1.z + b1.z); u1.w = f2b((v[7]-mu)*rcp*g1.w + b1.w);
  *(ushort4*)xr = u0; *(ushort4*)(xr + 4) = u1;
}

// final: LN(x19b row b, bf16 in) -> W_pre -> denorm -> W_dec
__global__ __launch_bounds__(64) void final_kernel(
    const unsigned short* __restrict__ x19,
    const float* __restrict__ g, const float* __restrict__ be,
    const float* __restrict__ W_pre, const float* __restrict__ b_pre,
    const float* __restrict__ mean, const float* __restrict__ stdv,
    const float* __restrict__ W_dec, const float* __restrict__ b_dec,
    float* __restrict__ out)
{
  const int b = blockIdx.x;
  const int lane = threadIdx.x;
  const unsigned short* xr = x19 + (size_t)b * DD;
  float vals[8];
  float s = 0.f;
#pragma unroll
  for (int j = 0; j < 8; ++j){ vals[j] = b2f(xr[lane + j*64]); s += vals[j]; }
  s = wsum(s);
  const float mu = s * (1.f/DD);
  float vs = 0.f;
#pragma unroll
  for (int j = 0; j < 8; ++j){ float d = vals[j]-mu; vs += d*d; }
  vs = wsum(vs);
  const float rs = rsqrtf(vs*(1.f/DD) + 1e-5f);
#pragma unroll
  for (int j = 0; j < 8; ++j){ int d0 = lane + j*64; vals[j] = (vals[j]-mu)*rs*g[d0] + be[d0]; }
  float accb = 0.f;
  for (int f = 0; f < FE; ++f){
    float d = 0.f;
#pragma unroll
    for (int j = 0; j < 8; ++j){ int d0 = lane + j*64; d += vals[j]*W_pre[f*DD + d0]; }
    d = wsum(d);
    float o = (d + b_pre[f]) * stdv[b*FE + f] + mean[b*FE + f];
    accb += o * W_dec[f];
  }
  if (lane == 0) out[b] = accb + b_dec[0];
}

extern "C" void kernel_launch(void* const* d_in, const int* in_sizes, int n_in,
                              void* d_out, int out_size, void* d_ws, size_t ws_size,
                              hipStream_t stream) {
  const float* src     = (const float*)d_in[0];
  const float* W_feat  = (const float*)d_in[1];
  const float* b_feat  = (const float*)d_in[2];
  const float* tau_conv= (const float*)d_in[3];
  const float* tau_W0  = (const float*)d_in[4];
  const float* tau_b0  = (const float*)d_in[5];
  const float* tau_W1  = (const float*)d_in[6];
  const float* tau_b1  = (const float*)d_in[7];
  const float* tau_W2  = (const float*)d_in[8];
  const float* del_conv= (const float*)d_in[9];
  const float* del_W0  = (const float*)d_in[10];
  const float* del_b0  = (const float*)d_in[11];
  const float* del_W1  = (const float*)d_in[12];
  const float* del_b1  = (const float*)d_in[13];
  const float* del_W2  = (const float*)d_in[14];
  const float* Wq = (const float*)d_in[15]; const float* bq = (const float*)d_in[16];
  const float* Wk = (const float*)d_in[17]; const float* bk = (const float*)d_in[18];
  const float* Wv = (const float*)d_in[19]; const float* bv = (const float*)d_in[20];
  const float* Wo = (const float*)d_in[21]; const float* bo = (const float*)d_in[22];
  const float* Wc1= (const float*)d_in[23]; const float* bc1= (const float*)d_in[24];
  const float* Wc2= (const float*)d_in[25]; const float* bc2= (const float*)d_in[26];
  const float* ln1_g=(const float*)d_in[27]; const float* ln1_b=(const float*)d_in[28];
  const float* ln2_g=(const float*)d_in[29]; const float* ln2_b=(const float*)d_in[30];
  const float* lnf_g=(const float*)d_in[31]; const float* lnf_b=(const float*)d_in[32];
  const float* W_pre=(const float*)d_in[33]; const float* b_pre=(const float*)d_in[34];
  const float* W_dec=(const float*)d_in[35]; const float* b_dec=(const float*)d_in[36];
  float* out = (float*)d_out;

  // workspace plan: per-seq = 5120 (xb) + 20480 (union).
  auto need_floats = [](size_t cb)->size_t{
    size_t fl = 10240 + 2*(size_t)BB*FE;   // pe + stats
    fl += 4718592 + 4608;                  // bf16 weights + bqkv
    fl += 2*(size_t)BB*40;                 // z_tau, z_del
    fl += 2*(size_t)BB*DD;                 // h_a, h_b
    fl += BB + (size_t)BB*FE;              // taub, delta
    fl += cb*25600;                        // xb + union
    fl += 64*64;
    return fl;
  };
  size_t maxCB = BB;
  while (maxCB > 64 && need_floats(maxCB)*4 > ws_size) maxCB -= 64;
  size_t nch = (BB + maxCB - 1) / maxCB;
  size_t CB = ((BB + nch - 1) / nch + 63) & ~(size_t)63;
  if (CB > maxCB) CB = maxCB;

  float* w = (float*)d_ws;
  size_t off = 0;
  auto take = [&](size_t n){ float* p = w + off; off += (n + 63) & ~(size_t)63; return p; };
  float* pe    = take(LL*DD);
  float* meanG = take((size_t)BB*FE);
  float* stdvG = take((size_t)BB*FE);
  unsigned short* Wqkvb = (unsigned short*)take((size_t)NLAY*1536*DD/2);
  unsigned short* Wob   = (unsigned short*)take((size_t)NLAY*DD*DD/2);
  unsigned short* Wc1b  = (unsigned short*)take((size_t)NLAY*FFD*DD/2);
  unsigned short* Wc2b  = (unsigned short*)take((size_t)NLAY*DD*FFD/2);
  float* bqkv  = take(NLAY*1536);
  float* z_tau = take((size_t)BB*40);
  float* z_del = take((size_t)BB*40);
  float* h_a   = take((size_t)BB*DD);
  float* h_b   = take((size_t)BB*DD);
  float* taubG = take(BB);
  float* deltaG= take((size_t)BB*FE);
  unsigned short* xb = (unsigned short*)take(CB*LL*DD/2);
  float* unionBuf = take(CB*20480);
  float* sbuf = unionBuf;                                           // [cb,400] fp32
  unsigned short* qkvb = (unsigned short*)unionBuf;                 // [cm,1536] bf16
  unsigned short* hb   = (unsigned short*)unionBuf;                 // [cm,2048] bf16
  unsigned short* kvb  = (unsigned short*)unionBuf;                 // [cm,1024] bf16
  unsigned short* q19b = (unsigned short*)(unionBuf + CB*10240);    // [cb,512] bf16
  unsigned short* o19b = (unsigned short*)(unionBuf + CB*10496);    // [cb,512] bf16
  unsigned short* hb19 = (unsigned short*)(unionBuf + CB*10752);    // [cb,2048] bf16
  unsigned short* x19b = (unsigned short*)(unionBuf + CB*11776);    // [cb,512] bf16

  // ---- whole-batch prep ----
  pe_kernel<<<20, 256, 0, stream>>>(pe);
  stats_kernel<<<(BB*FE + 255)/256, 256, 0, stream>>>(src, meanG, stdvG, BB*FE);
  {
    const int nqkv = DD*DD;
    for (int l = 0; l < NLAY; ++l) {
      cvt_bf16_kernel<<<(nqkv+255)/256, 256, 0, stream>>>(Wq + (size_t)l*nqkv, Wqkvb + (size_t)l*1536*DD, nqkv);
      cvt_bf16_kernel<<<(nqkv+255)/256, 256, 0, stream>>>(Wk + (size_t)l*nqkv, Wqkvb + (size_t)l*1536*DD + (size_t)512*DD, nqkv);
      cvt_bf16_kernel<<<(nqkv+255)/256, 256, 0, stream>>>(Wv + (size_t)l*nqkv, Wqkvb + (size_t)l*1536*DD + (size_t)1024*DD, nqkv);
    }
    int n1 = NLAY*DD*DD, n2 = NLAY*FFD*DD;
    cvt_bf16_kernel<<<(n1+255)/256, 256, 0, stream>>>(Wo, Wob, n1);
    cvt_bf16_kernel<<<(n2+255)/256, 256, 0, stream>>>(Wc1, Wc1b, n2);
    cvt_bf16_kernel<<<(n2+255)/256, 256, 0, stream>>>(Wc2, Wc2b, n2);
    concat_bias_kernel<<<(NLAY*1536+255)/256, 256, 0, stream>>>(bq, bk, bv, bqkv);
  }
  {
    const dim3 gP(8, BB/64);
    convz_kernel<<<BB, 64, 0, stream>>>(src, tau_conv, del_conv, meanG, stdvG, z_tau, z_del);
    gemm_xwt<true,true,false><<<gP, 256, 0, stream>>>(z_tau,40, tau_W0,40, tau_b0, h_a,DD, BB,DD,40, nullptr,nullptr);
    gemm_xwt<true,true,false><<<gP, 256, 0, stream>>>(h_a,DD, tau_W1,DD, tau_b1, h_b,DD, BB,DD,DD, nullptr,nullptr);
    tau_head<<<BB/4, 256, 0, stream>>>(h_b, tau_W2, taubG);
    gemm_xwt<true,true,false><<<gP, 256, 0, stream>>>(z_del,40, del_W0,40, del_b0, h_a,DD, BB,DD,40, nullptr,nullptr);
    gemm_xwt<true,true,false><<<gP, 256, 0, stream>>>(h_a,DD, del_W1,DD, del_b1, h_b,DD, BB,DD,DD, nullptr,nullptr);
    delta_head<<<BB, 256, 0, stream>>>(h_b, del_W2, deltaG);
  }

  const int iL = NLAY - 1;

  for (size_t b0 = 0; b0 < BB; b0 += CB) {
    const size_t cb = (BB - b0 < CB) ? (BB - b0) : CB;   // multiple of 64
    const int cm = (int)(cb * LL);                        // multiple of 1280
    const float* srcC  = src + b0*LL*FE;
    const float* meanC = meanG + b0*FE;
    const float* stdvC = stdvG + b0*FE;
    const float* taub  = taubG + b0;
    const float* delta = deltaG + b0*FE;

    const dim3 gEmb(8, cm/64);
    const dim3 gQKV(1536/128, cm/128);
    const dim3 gD(DD/128, cm/128);
    const dim3 gF1(FFD/128, cm/128);
    const dim3 gKV(1024/128, cm/128);
    const dim3 g19D(DD/128, (int)cb/64);
    const dim3 g19F(FFD/128, (int)cb/64);

    snorm_kernel<<<(int)((cb*LL*FE + 255)/256), 256, 0, stream>>>(srcC, meanC, stdvC, sbuf, (int)(cb*LL*FE));
    // embedding: xb = bf16(s @ W_feat^T + b_feat + pe)
    gemm_xwt<false,true,true><<<gEmb, 256, 0, stream>>>(sbuf,FE, W_feat,FE, b_feat, nullptr,DD, cm,DD,FE, pe, xb);

    // layers 0..NLAY-2 (full width)
    for (int i = 0; i < iL; ++i) {
      const size_t wOfs = (size_t)i * DD * DD;
      const size_t fOfs = (size_t)i * FFD * DD;
      bgemm<false,true,false><<<gQKV, 256, 0, stream>>>(xb,DD, Wqkvb + (size_t)i*1536*DD,DD, bqkv + i*1536, nullptr,0, qkvb,1536, DD);
      attn_kernel<<<(int)cb*HH, 256, 0, stream>>>(qkvb, taub, delta);
      // O-proj: xb = bf16(o @ Wo^T + bo + xb)  (o = qkvb cols 0..511)
      bgemm<false,true,true><<<gD, 256, 0, stream>>>(qkvb,1536, Wob+wOfs,DD, bo+i*DD, xb,DD, xb,DD, DD);
      ln_bf16_kernel<<<cm/4, 256, 0, stream>>>(xb, ln1_g+i*DD, ln1_b+i*DD);
      // FFN1: hb = relu(xb @ Wc1^T + bc1)  [cm,2048]
      bgemm<true,true,false><<<gF1, 256, 0, stream>>>(xb,DD, Wc1b+fOfs,DD, bc1+i*FFD, nullptr,0, hb,FFD, DD);
      // FFN2: xb = bf16(hb @ Wc2^T + bc2 + xb), K=2048
      bgemm<false,true,true><<<gD, 256, 0, stream>>>(hb,FFD, Wc2b+fOfs,FFD, bc2+i*DD, xb,DD, xb,DD, FFD);
      ln_bf16_kernel<<<cm/4, 256, 0, stream>>>(xb, ln2_g+i*DD, ln2_b+i*DD);
    }

    // last layer: only row l=19 feeds the output
    {
      const size_t wOfs = (size_t)iL * DD * DD;
      const size_t fOfs = (size_t)iL * FFD * DD;
      bgemm<false,true,false><<<gKV, 256, 0, stream>>>(xb,DD, Wqkvb + (size_t)iL*1536*DD + (size_t)512*DD,DD, bqkv + iL*1536 + 512, nullptr,0, kvb,1024, DD);
      bgemm64<false,true,false><<<g19D, 256, 0, stream>>>(xb + 19*DD, LL*DD, Wqkvb + (size_t)iL*1536*DD,DD, bqkv + iL*1536, nullptr,0, q19b,DD, DD);
      attn19_kernel<<<(int)cb*HH, 64, 0, stream>>>(kvb, q19b, o19b, taub, delta);
      bgemm64<false,true,true><<<g19D, 256, 0, stream>>>(o19b,DD, Wob+wOfs,DD, bo+iL*DD, xb + 19*DD, LL*DD, x19b,DD, DD);
      ln_bf16_kernel<<<(int)cb/4, 256, 0, stream>>>(x19b, ln1_g+iL*DD, ln1_b+iL*DD);
      bgemm64<true,true,false><<<g19F, 256, 0, stream>>>(x19b,DD, Wc1b+fOfs,DD, bc1+iL*FFD, nullptr,0, hb19,FFD, DD);
      bgemm64<false,true,true><<<g19D, 256, 0, stream>>>(hb19,FFD, Wc2b+fOfs,FFD, bc2+iL*DD, x19b,DD, x19b,DD, FFD);
      ln_bf16_kernel<<<(int)cb/4, 256, 0, stream>>>(x19b, ln2_g+iL*DD, ln2_b+iL*DD);
    }

    final_kernel<<<(int)cb, 64, 0, stream>>>(x19b, lnf_g, lnf_b, W_pre, b_pre, meanC, stdvC, W_dec, b_dec, out + b0);
  }
}

// Round 15
// 2515.137 us; speedup vs baseline: 1.0419x; 1.0126x over previous
//
#include <hip/hip_runtime.h>
#include <math.h>
#include <stdint.h>

// NSTransformer forward — FINAL banked configuration (= round-12 state, best
// measured: 2518.8 us). bf16-MFMA GEMMs (128x128 tile, 2-phase double-buffer —
// proven best; 256-tile r11, 4-buf r13, 3-buf r14 pipelines all regressed),
// bf16 residual stream, fused QKV, row-19-only last layer, whole-batch
// projector, balanced 64-granular chunking, XCD-swizzled grids.
#define BB 4096
#define LL 20
#define FE 20
#define DD 512
#define HH 8
#define DHD 64
#define FFD 2048
#define NLAY 3

typedef __bf16 bf16x8 __attribute__((ext_vector_type(8)));
typedef float f32x4 __attribute__((ext_vector_type(4)));

// Direct C-style casts (addrspacecast) — NOT via uintptr_t (round-3 abort cause).
__device__ __forceinline__ void gload_lds16(const unsigned short* g, unsigned short* l){
  __builtin_amdgcn_global_load_lds(
      (const __attribute__((address_space(1))) void*)g,
      (__attribute__((address_space(3))) void*)l, 16, 0, 0);
}

__device__ __forceinline__ float wsum(float v){
#pragma unroll
  for (int o = 32; o > 0; o >>= 1) v += __shfl_xor(v, o, 64);
  return v;
}

__device__ __forceinline__ unsigned short f2b(float f){
  unsigned u = __float_as_uint(f);
  u += 0x7FFFu + ((u >> 16) & 1u);
  return (unsigned short)(u >> 16);
}
__device__ __forceinline__ float b2f(unsigned short b){
  return __uint_as_float(((unsigned)b) << 16);
}

// XCD-aware bijective block swizzle (m204).
__device__ __forceinline__ int2 xcd_swz(){
  const int nx = gridDim.x;
  const int nwg = nx * gridDim.y;
  const int orig = blockIdx.y * nx + blockIdx.x;
  const int q = nwg >> 3, r = nwg & 7;
  const int xcd = orig & 7, idx = orig >> 3;
  const int wg = (xcd < r ? xcd*(q+1) : r*(q+1) + (xcd-r)*q) + idx;
  return make_int2(wg % nx, wg / nx);
}

// ============ bf16 MFMA GEMM, 128x128 tile; bf16 out; optional bf16 residual ============
template<bool RELU, bool BIAS, bool RES>
__global__ __launch_bounds__(256) void bgemm(
    const unsigned short* __restrict__ A, int lda,
    const unsigned short* __restrict__ W, int ldw,
    const float* __restrict__ bias,
    const unsigned short* res, int ldr,
    unsigned short* __restrict__ Cout, int ldc, int K)
{
  __shared__ __align__(16) unsigned short Asm[2][128*32];
  __shared__ __align__(16) unsigned short Bsm[2][128*32];
  const int2 swz = xcd_swz();
  const int bn = swz.x << 7, bm = swz.y << 7;
  const int tid = threadIdx.x;
  const int wave = tid >> 6, lane = tid & 63;
  const int wr = wave >> 1, wc = wave & 1;
  const int sr = lane >> 2, slot = lane & 3;
  const int rg = lane & 15, cg = lane >> 4;

  f32x4 acc[4][4];
#pragma unroll
  for (int i = 0; i < 4; ++i)
#pragma unroll
    for (int j = 0; j < 4; ++j) acc[i][j] = (f32x4){0.f,0.f,0.f,0.f};

  auto stage = [&](int kt, int b){
    const int k0 = kt << 5;
#pragma unroll
    for (int i = 0; i < 2; ++i) {
      const int r  = (i<<6) + (wave<<4) + sr;
      const int ch = slot ^ ((r>>1)&3);
      gload_lds16(A + (size_t)(bm + r)*lda + k0 + (ch<<3),
                  &Asm[b][((i<<6) + (wave<<4))*32]);
      gload_lds16(W + (size_t)(bn + r)*ldw + k0 + (ch<<3),
                  &Bsm[b][((i<<6) + (wave<<4))*32]);
    }
  };

  auto compute = [&](int b){
    bf16x8 af[4], bfr[4];
#pragma unroll
    for (int mi = 0; mi < 4; ++mi){
      int r = (wr<<6) + (mi<<4) + rg;
      af[mi] = *(const bf16x8*)&Asm[b][r*32 + ((cg ^ ((r>>1)&3))<<3)];
    }
#pragma unroll
    for (int ni = 0; ni < 4; ++ni){
      int r = (wc<<6) + (ni<<4) + rg;
      bfr[ni] = *(const bf16x8*)&Bsm[b][r*32 + ((cg ^ ((r>>1)&3))<<3)];
    }
#pragma unroll
    for (int mi = 0; mi < 4; ++mi)
#pragma unroll
      for (int ni = 0; ni < 4; ++ni)
        acc[mi][ni] = __builtin_amdgcn_mfma_f32_16x16x32_bf16(af[mi], bfr[ni], acc[mi][ni], 0, 0, 0);
  };

  const int nt = K >> 5;
  stage(0, 0);
  __syncthreads();
  int cur = 0;
  for (int t = 0; t < nt; ++t){
    if (t + 1 < nt) stage(t + 1, cur ^ 1);
    compute(cur);
    __syncthreads();
    cur ^= 1;
  }

#pragma unroll
  for (int mi = 0; mi < 4; ++mi){
#pragma unroll
    for (int ni = 0; ni < 4; ++ni){
      const int row0 = bm + (wr<<6) + (mi<<4) + (cg<<2);
      const int col  = bn + (wc<<6) + (ni<<4) + rg;
      float bv = BIAS ? bias[col] : 0.f;
#pragma unroll
      for (int j = 0; j < 4; ++j){
        float v = acc[mi][ni][j] + bv;
        if (RES)  v += b2f(res[(size_t)(row0+j)*ldr + col]);
        if (RELU) v = fmaxf(v, 0.f);
        Cout[(size_t)(row0+j)*ldc + col] = f2b(v);
      }
    }
  }
}

// ============ bf16 MFMA GEMM, 64x128 tile (row-19 tail) ============
template<bool RELU, bool BIAS, bool RES>
__global__ __launch_bounds__(256) void bgemm64(
    const unsigned short* __restrict__ A, int lda,
    const unsigned short* __restrict__ W, int ldw,
    const float* __restrict__ bias,
    const unsigned short* res, int ldr,
    unsigned short* __restrict__ Cout, int ldc, int K)
{
  __shared__ __align__(16) unsigned short Asm[2][64*32];
  __shared__ __align__(16) unsigned short Bsm[2][128*32];
  const int2 swz = xcd_swz();
  const int bn = swz.x << 7, bm = swz.y << 6;
  const int tid = threadIdx.x;
  const int wave = tid >> 6, lane = tid & 63;
  const int sr = lane >> 2, slot = lane & 3;
  const int rg = lane & 15, cg = lane >> 4;

  f32x4 acc[4][2];
#pragma unroll
  for (int i = 0; i < 4; ++i)
#pragma unroll
    for (int j = 0; j < 2; ++j) acc[i][j] = (f32x4){0.f,0.f,0.f,0.f};

  auto stage = [&](int kt, int b){
    const int k0 = kt << 5;
    {
      const int r  = (wave<<4) + sr;
      const int ch = slot ^ ((r>>1)&3);
      gload_lds16(A + (size_t)(bm + r)*lda + k0 + (ch<<3),
                  &Asm[b][(wave<<4)*32]);
    }
#pragma unroll
    for (int i = 0; i < 2; ++i) {
      const int r  = (i<<6) + (wave<<4) + sr;
      const int ch = slot ^ ((r>>1)&3);
      gload_lds16(W + (size_t)(bn + r)*ldw + k0 + (ch<<3),
                  &Bsm[b][((i<<6) + (wave<<4))*32]);
    }
  };

  auto compute = [&](int b){
    bf16x8 af[4], bfr[2];
#pragma unroll
    for (int mi = 0; mi < 4; ++mi){
      int r = (mi<<4) + rg;
      af[mi] = *(const bf16x8*)&Asm[b][r*32 + ((cg ^ ((r>>1)&3))<<3)];
    }
#pragma unroll
    for (int ni = 0; ni < 2; ++ni){
      int r = (wave<<5) + (ni<<4) + rg;
      bfr[ni] = *(const bf16x8*)&Bsm[b][r*32 + ((cg ^ ((r>>1)&3))<<3)];
    }
#pragma unroll
    for (int mi = 0; mi < 4; ++mi)
#pragma unroll
      for (int ni = 0; ni < 2; ++ni)
        acc[mi][ni] = __builtin_amdgcn_mfma_f32_16x16x32_bf16(af[mi], bfr[ni], acc[mi][ni], 0, 0, 0);
  };

  const int nt = K >> 5;
  stage(0, 0);
  __syncthreads();
  int cur = 0;
  for (int t = 0; t < nt; ++t){
    if (t + 1 < nt) stage(t + 1, cur ^ 1);
    compute(cur);
    __syncthreads();
    cur ^= 1;
  }

#pragma unroll
  for (int mi = 0; mi < 4; ++mi){
#pragma unroll
    for (int ni = 0; ni < 2; ++ni){
      const int row0 = bm + (mi<<4) + (cg<<2);
      const int col  = bn + (wave<<5) + (ni<<4) + rg;
      float bv = BIAS ? bias[col] : 0.f;
#pragma unroll
      for (int j = 0; j < 4; ++j){
        float v = acc[mi][ni][j] + bv;
        if (RES)  v += b2f(res[(size_t)(row0+j)*ldr + col]);
        if (RELU) v = fmaxf(v, 0.f);
        Cout[(size_t)(row0+j)*ldc + col] = f2b(v);
      }
    }
  }
}

// ============ fp32 tiled GEMM (projector fp32 out; embed PE -> bf16-only out) ============
template<bool RELU, bool BIAS, bool PE>
__global__ __launch_bounds__(256) void gemm_xwt(
    const float* __restrict__ A, int lda,
    const float* __restrict__ W, int ldw,
    const float* __restrict__ bias,
    float* __restrict__ C, int ldc,
    int M, int N, int K,
    const float* __restrict__ pe, unsigned short* __restrict__ xbout)
{
  __shared__ float As[16][72];
  __shared__ float Ws[16][72];
  const int bm = blockIdx.y << 6, bn = blockIdx.x << 6;
  const int tid = threadIdx.x;
  const int tx = tid & 15, ty = tid >> 4;
  const int lr = tid >> 2;
  const int lc = (tid & 3) << 2;
  float acc[4][4] = {{0.f}};
  const float* Ap = A + (size_t)(bm + lr) * lda;
  const float* Wp = W + (size_t)(bn + lr) * ldw;
  for (int k0 = 0; k0 < K; k0 += 16) {
    float4 av, wv;
    if (k0 + 16 <= K) {
      av = *(const float4*)(Ap + k0 + lc);
      wv = *(const float4*)(Wp + k0 + lc);
    } else {
      float aa[4] = {0,0,0,0}, ww[4] = {0,0,0,0};
#pragma unroll
      for (int j = 0; j < 4; ++j){ int kk = k0 + lc + j; if (kk < K){ aa[j] = Ap[kk]; ww[j] = Wp[kk]; } }
      av = make_float4(aa[0],aa[1],aa[2],aa[3]);
      wv = make_float4(ww[0],ww[1],ww[2],ww[3]);
    }
    As[lc+0][lr]=av.x; As[lc+1][lr]=av.y; As[lc+2][lr]=av.z; As[lc+3][lr]=av.w;
    Ws[lc+0][lr]=wv.x; Ws[lc+1][lr]=wv.y; Ws[lc+2][lr]=wv.z; Ws[lc+3][lr]=wv.w;
    __syncthreads();
#pragma unroll
    for (int k = 0; k < 16; ++k) {
      const float4 a = *(const float4*)(&As[k][ty<<2]);
      const float4 b = *(const float4*)(&Ws[k][tx<<2]);
      acc[0][0]+=a.x*b.x; acc[0][1]+=a.x*b.y; acc[0][2]+=a.x*b.z; acc[0][3]+=a.x*b.w;
      acc[1][0]+=a.y*b.x; acc[1][1]+=a.y*b.y; acc[1][2]+=a.y*b.z; acc[1][3]+=a.y*b.w;
      acc[2][0]+=a.z*b.x; acc[2][1]+=a.z*b.y; acc[2][2]+=a.z*b.z; acc[2][3]+=a.z*b.w;
      acc[3][0]+=a.w*b.x; acc[3][1]+=a.w*b.y; acc[3][2]+=a.w*b.z; acc[3][3]+=a.w*b.w;
    }
    __syncthreads();
  }
#pragma unroll
  for (int i = 0; i < 4; ++i) {
    const int m = bm + (ty<<2) + i;
#pragma unroll
    for (int j = 0; j < 4; ++j) {
      const int col = bn + (tx<<2) + j;
      float v = acc[i][j];
      if (BIAS) v += bias[col];
      if (PE)   v += pe[(m % LL)*DD + col];
      if (RELU) v = fmaxf(v, 0.f);
      if (PE) xbout[(size_t)m*ldc + col] = f2b(v);
      else    C[(size_t)m*ldc + col] = v;
    }
  }
}

// ============ misc small kernels ============
__global__ void cvt_bf16_kernel(const float* __restrict__ in, unsigned short* __restrict__ out, int n){
  int i = blockIdx.x * 256 + threadIdx.x;
  if (i < n) out[i] = f2b(in[i]);
}

__global__ void concat_bias_kernel(const float* __restrict__ bq, const float* __restrict__ bk,
                                   const float* __restrict__ bv, float* __restrict__ bqkv){
  int i = blockIdx.x * 256 + threadIdx.x;
  if (i >= NLAY*1536) return;
  int l = i / 1536, r = i % 1536;
  int s = r >> 9, j = r & 511;
  const float* srcp = (s == 0) ? bq : (s == 1) ? bk : bv;
  bqkv[i] = srcp[l*DD + j];
}

__global__ void pe_kernel(float* __restrict__ pe){
  int i = blockIdx.x * 256 + threadIdx.x;
  int l = i >> 8, hd = i & 255;
  float dv = expf((2.f * hd) * (-9.210340371976184f / 512.f));
  float a = (float)l * dv;
  pe[l*DD + 2*hd]     = sinf(a);
  pe[l*DD + 2*hd + 1] = cosf(a);
}

__global__ void stats_kernel(const float* __restrict__ src, float* __restrict__ mean,
                             float* __restrict__ stdv, int nbf){
  int i = blockIdx.x * 256 + threadIdx.x;
  if (i >= nbf) return;
  int b = i / FE, f = i % FE;
  const float* p = src + (size_t)b * (LL*FE) + f;
  float v[LL]; float s = 0.f;
#pragma unroll
  for (int l = 0; l < LL; ++l){ v[l] = p[l*FE]; s += v[l]; }
  float m = s * (1.f/LL);
  float q = 0.f;
#pragma unroll
  for (int l = 0; l < LL; ++l){ float d = v[l]-m; q += d*d; }
  mean[i] = m;
  stdv[i] = sqrtf(q * (1.f/LL) + 1e-5f);
}

__global__ void snorm_kernel(const float* __restrict__ src, const float* __restrict__ mean,
                             const float* __restrict__ stdv, float* __restrict__ s, int n){
  int i = blockIdx.x * 256 + threadIdx.x;
  if (i >= n) return;
  int b = i / (LL*FE);
  int f = i % FE;
  int bf = b*FE + f;
  s[i] = (src[i] - mean[bf]) / stdv[bf];
}

__global__ __launch_bounds__(64) void convz_kernel(
    const float* __restrict__ src, const float* __restrict__ wt, const float* __restrict__ wd,
    const float* __restrict__ mean, const float* __restrict__ stdv,
    float* __restrict__ z_tau, float* __restrict__ z_del)
{
  int b = blockIdx.x;
  __shared__ float ss[LL*FE];
  __shared__ float wct[LL*3], wcd[LL*3];
  for (int idx = threadIdx.x; idx < LL*FE; idx += 64) ss[idx] = src[(size_t)b*LL*FE + idx];
  if (threadIdx.x < 60){ wct[threadIdx.x] = wt[threadIdx.x]; wcd[threadIdx.x] = wd[threadIdx.x]; }
  __syncthreads();
  if (threadIdx.x < 40) {
    int f = threadIdx.x % FE;
    bool isdel = threadIdx.x >= FE;
    const float* w = isdel ? wcd : wct;
    int fm = (f + FE - 1) % FE, fp = (f + 1) % FE;
    float acc = 0.f;
#pragma unroll
    for (int t = 0; t < LL; ++t){
      const float* r = ss + t*FE;
      acc += r[fm]*w[t*3+0] + r[f]*w[t*3+1] + r[fp]*w[t*3+2];
    }
    if (isdel){ z_del[b*40 + f] = acc; z_del[b*40 + 20 + f] = mean[b*FE + f]; }
    else      { z_tau[b*40 + f] = acc; z_tau[b*40 + 20 + f] = stdv[b*FE + f]; }
  }
}

__global__ __launch_bounds__(256) void tau_head(const float* __restrict__ h, const float* __restrict__ W2, float* __restrict__ tau){
  const int b = (blockIdx.x << 2) + (threadIdx.x >> 6);
  const int lane = threadIdx.x & 63;
  const float* hb = h + (size_t)b * DD;
  float s = 0.f;
#pragma unroll
  for (int j = 0; j < 8; ++j){ int d0 = lane + j*64; s += hb[d0]*W2[d0]; }
  s = wsum(s);
  if (lane == 0) tau[b] = expf(s);
}

__global__ __launch_bounds__(256) void delta_head(const float* __restrict__ h, const float* __restrict__ W2, float* __restrict__ delta){
  const int b = blockIdx.x;
  const int w = threadIdx.x >> 6, lane = threadIdx.x & 63;
  const float* hb = h + (size_t)b * DD;
  for (int f = w; f < FE; f += 4){
    float s = 0.f;
#pragma unroll
    for (int j = 0; j < 8; ++j){ int d0 = lane + j*64; s += hb[d0]*W2[(size_t)f*DD + d0]; }
    s = wsum(s);
    if (lane == 0) delta[b*FE + f] = s;
  }
}

// ============ attention (full, layers 0..NLAY-2); o IN PLACE over q ============
__global__ __launch_bounds__(256) void attn_kernel(
    unsigned short* __restrict__ qkv,
    const float* __restrict__ tau, const float* __restrict__ delta)
{
  const int bh = blockIdx.x;
  const int b = bh >> 3, h = bh & 7;
  __shared__ float qs[LL][68];
  __shared__ float kt[DHD][25];
  __shared__ float vs[LL][DHD];
  __shared__ float ps[LL][LL+1];
  const size_t base = (size_t)b * LL * 1536 + h * DHD;
  unsigned short* qg = qkv + base;
  const unsigned short* kg = qkv + base + 512;
  const unsigned short* vg = qkv + base + 1024;

  for (int it = threadIdx.x; it < LL*16; it += 256) {
    const int l = it >> 4, c = it & 15;
    const ushort4 qv = *(const ushort4*)(qg + l*1536 + c*4);
    const ushort4 kv = *(const ushort4*)(kg + l*1536 + c*4);
    const ushort4 vv = *(const ushort4*)(vg + l*1536 + c*4);
    qs[l][c*4+0]=b2f(qv.x); qs[l][c*4+1]=b2f(qv.y); qs[l][c*4+2]=b2f(qv.z); qs[l][c*4+3]=b2f(qv.w);
    kt[c*4+0][l]=b2f(kv.x); kt[c*4+1][l]=b2f(kv.y); kt[c*4+2][l]=b2f(kv.z); kt[c*4+3][l]=b2f(kv.w);
    vs[l][c*4+0]=b2f(vv.x); vs[l][c*4+1]=b2f(vv.y); vs[l][c*4+2]=b2f(vv.z); vs[l][c*4+3]=b2f(vv.w);
  }
  __syncthreads();

  const float ta = tau[b];
  for (int idx = threadIdx.x; idx < LL*LL; idx += 256) {
    const int l = idx / LL, s2 = idx % LL;
    float d = 0.f;
#pragma unroll
    for (int e = 0; e < DHD; ++e) d += qs[l][e]*kt[e][s2];
    ps[l][s2] = 0.125f * (d * ta + delta[b*FE + s2]);
  }
  __syncthreads();

  if (threadIdx.x < LL) {
    const int l = threadIdx.x;
    float m = -1e30f;
#pragma unroll
    for (int s2 = 0; s2 < LL; ++s2) m = fmaxf(m, ps[l][s2]);
    float sum = 0.f;
#pragma unroll
    for (int s2 = 0; s2 < LL; ++s2){ float e2 = expf(ps[l][s2]-m); ps[l][s2] = e2; sum += e2; }
    const float r = 1.f / sum;
#pragma unroll
    for (int s2 = 0; s2 < LL; ++s2) ps[l][s2] *= r;
  }
  __syncthreads();

  for (int it = threadIdx.x; it < LL*16; it += 256) {
    const int l = it >> 4, c = it & 15;
    float4 o = {0.f,0.f,0.f,0.f};
#pragma unroll
    for (int s2 = 0; s2 < LL; ++s2) {
      const float p = ps[l][s2];
      const float4 vv = *(const float4*)&vs[s2][c*4];
      o.x += p*vv.x; o.y += p*vv.y; o.z += p*vv.z; o.w += p*vv.w;
    }
    ushort4 ov;
    ov.x = f2b(o.x); ov.y = f2b(o.y); ov.z = f2b(o.z); ov.w = f2b(o.w);
    *(ushort4*)(qg + l*1536 + c*4) = ov;
  }
}

// ============ attention, single query row l=19 (last layer) ============
__global__ __launch_bounds__(64) void attn19_kernel(
    const unsigned short* __restrict__ kvb, const unsigned short* __restrict__ q19,
    unsigned short* __restrict__ o19,
    const float* __restrict__ tau, const float* __restrict__ delta)
{
  const int bh = blockIdx.x;
  const int b = bh >> 3, h = bh & 7;
  __shared__ float ks[LL][DHD], vs[LL][DHD];
  const unsigned short* kg = kvb + (size_t)b * LL * 1024 + h * DHD;
  const unsigned short* vg = kg + 512;
  for (int it = threadIdx.x; it < LL*16; it += 64) {
    const int l = it >> 4, c = it & 15;
    const ushort4 kv = *(const ushort4*)(kg + l*1024 + c*4);
    const ushort4 vv = *(const ushort4*)(vg + l*1024 + c*4);
    ks[l][c*4+0]=b2f(kv.x); ks[l][c*4+1]=b2f(kv.y); ks[l][c*4+2]=b2f(kv.z); ks[l][c*4+3]=b2f(kv.w);
    vs[l][c*4+0]=b2f(vv.x); vs[l][c*4+1]=b2f(vv.y); vs[l][c*4+2]=b2f(vv.z); vs[l][c*4+3]=b2f(vv.w);
  }
  __syncthreads();
  const int e = threadIdx.x;
  const float q = b2f(q19[(size_t)b*DD + h*DHD + e]);
  const float ta = tau[b];
  float p[LL];
  float m = -1e30f;
#pragma unroll
  for (int s2 = 0; s2 < LL; ++s2){
    float d = q * ks[s2][e];
    d = wsum(d);
    p[s2] = 0.125f * (d * ta + delta[b*FE + s2]);
    m = fmaxf(m, p[s2]);
  }
  float sum = 0.f;
#pragma unroll
  for (int s2 = 0; s2 < LL; ++s2){ p[s2] = expf(p[s2]-m); sum += p[s2]; }
  const float r = 1.f / sum;
  float o = 0.f;
#pragma unroll
  for (int s2 = 0; s2 < LL; ++s2) o += p[s2] * vs[s2][e];
  o19[(size_t)b*DD + h*DHD + e] = f2b(o * r);
}

// ============ LayerNorm rows of 512, bf16 in-place (fp32 stats) ============
__global__ __launch_bounds__(256) void ln_bf16_kernel(
    unsigned short* __restrict__ x, const float* __restrict__ g, const float* __restrict__ be)
{
  const int row = (blockIdx.x << 2) + (threadIdx.x >> 6);
  const int lane = threadIdx.x & 63;
  const int d0 = lane * 8;
  unsigned short* xr = x + (size_t)row * DD + d0;
  const ushort4 a = *(const ushort4*)xr;
  const ushort4 b = *(const ushort4*)(xr + 4);
  float v[8];
  v[0]=b2f(a.x); v[1]=b2f(a.y); v[2]=b2f(a.z); v[3]=b2f(a.w);
  v[4]=b2f(b.x); v[5]=b2f(b.y); v[6]=b2f(b.z); v[7]=b2f(b.w);
  float s = v[0]+v[1]+v[2]+v[3]+v[4]+v[5]+v[6]+v[7];
  s = wsum(s);
  const float mu = s * (1.f/DD);
  float q = 0.f;
#pragma unroll
  for (int j = 0; j < 8; ++j){ float d = v[j]-mu; q += d*d; }
  q = wsum(q);
  const float rcp = rsqrtf(q*(1.f/DD) + 1e-5f);
  const float4 g0 = *(const float4*)(g + d0), g1 = *(const float4*)(g + d0 + 4);
  const float4 b0 = *(const float4*)(be + d0), b1 = *(const float4*)(be + d0 + 4);
  ushort4 u0, u1;
  u0.x = f2b((v[0]-mu)*rcp*g0.x + b0.x); u0.y = f2b((v[1]-mu)*rcp*g0.y + b0.y);
  u0.z = f2b((v[2]-mu)*rcp*g0.z + b0.z); u0.w = f2b((v[3]-mu)*rcp*g0.w + b0.w);
  u1.x = f2b((v[4]-mu)*rcp*g1.x + b1.x); u1.y = f2b((v[5]-mu)*rcp*g1.y + b1.y);
  u1.z = f2b((v[6]-mu)*rcp*g1.z + b1.z); u1.w = f2b((v[7]-mu)*rcp*g1.w + b1.w);
  *(ushort4*)xr = u0; *(ushort4*)(xr + 4) = u1;
}

// final: LN(x19b row b, bf16 in) -> W_pre -> denorm -> W_dec
__global__ __launch_bounds__(64) void final_kernel(
    const unsigned short* __restrict__ x19,
    const float* __restrict__ g, const float* __restrict__ be,
    const float* __restrict__ W_pre, const float* __restrict__ b_pre,
    const float* __restrict__ mean, const float* __restrict__ stdv,
    const float* __restrict__ W_dec, const float* __restrict__ b_dec,
    float* __restrict__ out)
{
  const int b = blockIdx.x;
  const int lane = threadIdx.x;
  const unsigned short* xr = x19 + (size_t)b * DD;
  float vals[8];
  float s = 0.f;
#pragma unroll
  for (int j = 0; j < 8; ++j){ vals[j] = b2f(xr[lane + j*64]); s += vals[j]; }
  s = wsum(s);
  const float mu = s * (1.f/DD);
  float vs = 0.f;
#pragma unroll
  for (int j = 0; j < 8; ++j){ float d = vals[j]-mu; vs += d*d; }
  vs = wsum(vs);
  const float rs = rsqrtf(vs*(1.f/DD) + 1e-5f);
#pragma unroll
  for (int j = 0; j < 8; ++j){ int d0 = lane + j*64; vals[j] = (vals[j]-mu)*rs*g[d0] + be[d0]; }
  float accb = 0.f;
  for (int f = 0; f < FE; ++f){
    float d = 0.f;
#pragma unroll
    for (int j = 0; j < 8; ++j){ int d0 = lane + j*64; d += vals[j]*W_pre[f*DD + d0]; }
    d = wsum(d);
    float o = (d + b_pre[f]) * stdv[b*FE + f] + mean[b*FE + f];
    accb += o * W_dec[f];
  }
  if (lane == 0) out[b] = accb + b_dec[0];
}

extern "C" void kernel_launch(void* const* d_in, const int* in_sizes, int n_in,
                              void* d_out, int out_size, void* d_ws, size_t ws_size,
                              hipStream_t stream) {
  const float* src     = (const float*)d_in[0];
  const float* W_feat  = (const float*)d_in[1];
  const float* b_feat  = (const float*)d_in[2];
  const float* tau_conv= (const float*)d_in[3];
  const float* tau_W0  = (const float*)d_in[4];
  const float* tau_b0  = (const float*)d_in[5];
  const float* tau_W1  = (const float*)d_in[6];
  const float* tau_b1  = (const float*)d_in[7];
  const float* tau_W2  = (const float*)d_in[8];
  const float* del_conv= (const float*)d_in[9];
  const float* del_W0  = (const float*)d_in[10];
  const float* del_b0  = (const float*)d_in[11];
  const float* del_W1  = (const float*)d_in[12];
  const float* del_b1  = (const float*)d_in[13];
  const float* del_W2  = (const float*)d_in[14];
  const float* Wq = (const float*)d_in[15]; const float* bq = (const float*)d_in[16];
  const float* Wk = (const float*)d_in[17]; const float* bk = (const float*)d_in[18];
  const float* Wv = (const float*)d_in[19]; const float* bv = (const float*)d_in[20];
  const float* Wo = (const float*)d_in[21]; const float* bo = (const float*)d_in[22];
  const float* Wc1= (const float*)d_in[23]; const float* bc1= (const float*)d_in[24];
  const float* Wc2= (const float*)d_in[25]; const float* bc2= (const float*)d_in[26];
  const float* ln1_g=(const float*)d_in[27]; const float* ln1_b=(const float*)d_in[28];
  const float* ln2_g=(const float*)d_in[29]; const float* ln2_b=(const float*)d_in[30];
  const float* lnf_g=(const float*)d_in[31]; const float* lnf_b=(const float*)d_in[32];
  const float* W_pre=(const float*)d_in[33]; const float* b_pre=(const float*)d_in[34];
  const float* W_dec=(const float*)d_in[35]; const float* b_dec=(const float*)d_in[36];
  float* out = (float*)d_out;

  // workspace plan: per-seq = 5120 (xb) + 20480 (union).
  auto need_floats = [](size_t cb)->size_t{
    size_t fl = 10240 + 2*(size_t)BB*FE;   // pe + stats
    fl += 4718592 + 4608;                  // bf16 weights + bqkv
    fl += 2*(size_t)BB*40;                 // z_tau, z_del
    fl += 2*(size_t)BB*DD;                 // h_a, h_b
    fl += BB + (size_t)BB*FE;              // taub, delta
    fl += cb*25600;                        // xb + union
    fl += 64*64;
    return fl;
  };
  size_t maxCB = BB;
  while (maxCB > 64 && need_floats(maxCB)*4 > ws_size) maxCB -= 64;
  size_t nch = (BB + maxCB - 1) / maxCB;
  size_t CB = ((BB + nch - 1) / nch + 63) & ~(size_t)63;
  if (CB > maxCB) CB = maxCB;

  float* w = (float*)d_ws;
  size_t off = 0;
  auto take = [&](size_t n){ float* p = w + off; off += (n + 63) & ~(size_t)63; return p; };
  float* pe    = take(LL*DD);
  float* meanG = take((size_t)BB*FE);
  float* stdvG = take((size_t)BB*FE);
  unsigned short* Wqkvb = (unsigned short*)take((size_t)NLAY*1536*DD/2);
  unsigned short* Wob   = (unsigned short*)take((size_t)NLAY*DD*DD/2);
  unsigned short* Wc1b  = (unsigned short*)take((size_t)NLAY*FFD*DD/2);
  unsigned short* Wc2b  = (unsigned short*)take((size_t)NLAY*DD*FFD/2);
  float* bqkv  = take(NLAY*1536);
  float* z_tau = take((size_t)BB*40);
  float* z_del = take((size_t)BB*40);
  float* h_a   = take((size_t)BB*DD);
  float* h_b   = take((size_t)BB*DD);
  float* taubG = take(BB);
  float* deltaG= take((size_t)BB*FE);
  unsigned short* xb = (unsigned short*)take(CB*LL*DD/2);
  float* unionBuf = take(CB*20480);
  float* sbuf = unionBuf;                                           // [cb,400] fp32
  unsigned short* qkvb = (unsigned short*)unionBuf;                 // [cm,1536] bf16
  unsigned short* hb   = (unsigned short*)unionBuf;                 // [cm,2048] bf16
  unsigned short* kvb  = (unsigned short*)unionBuf;                 // [cm,1024] bf16
  unsigned short* q19b = (unsigned short*)(unionBuf + CB*10240);    // [cb,512] bf16
  unsigned short* o19b = (unsigned short*)(unionBuf + CB*10496);    // [cb,512] bf16
  unsigned short* hb19 = (unsigned short*)(unionBuf + CB*10752);    // [cb,2048] bf16
  unsigned short* x19b = (unsigned short*)(unionBuf + CB*11776);    // [cb,512] bf16

  // ---- whole-batch prep ----
  pe_kernel<<<20, 256, 0, stream>>>(pe);
  stats_kernel<<<(BB*FE + 255)/256, 256, 0, stream>>>(src, meanG, stdvG, BB*FE);
  {
    const int nqkv = DD*DD;
    for (int l = 0; l < NLAY; ++l) {
      cvt_bf16_kernel<<<(nqkv+255)/256, 256, 0, stream>>>(Wq + (size_t)l*nqkv, Wqkvb + (size_t)l*1536*DD, nqkv);
      cvt_bf16_kernel<<<(nqkv+255)/256, 256, 0, stream>>>(Wk + (size_t)l*nqkv, Wqkvb + (size_t)l*1536*DD + (size_t)512*DD, nqkv);
      cvt_bf16_kernel<<<(nqkv+255)/256, 256, 0, stream>>>(Wv + (size_t)l*nqkv, Wqkvb + (size_t)l*1536*DD + (size_t)1024*DD, nqkv);
    }
    int n1 = NLAY*DD*DD, n2 = NLAY*FFD*DD;
    cvt_bf16_kernel<<<(n1+255)/256, 256, 0, stream>>>(Wo, Wob, n1);
    cvt_bf16_kernel<<<(n2+255)/256, 256, 0, stream>>>(Wc1, Wc1b, n2);
    cvt_bf16_kernel<<<(n2+255)/256, 256, 0, stream>>>(Wc2, Wc2b, n2);
    concat_bias_kernel<<<(NLAY*1536+255)/256, 256, 0, stream>>>(bq, bk, bv, bqkv);
  }
  {
    const dim3 gP(8, BB/64);
    convz_kernel<<<BB, 64, 0, stream>>>(src, tau_conv, del_conv, meanG, stdvG, z_tau, z_del);
    gemm_xwt<true,true,false><<<gP, 256, 0, stream>>>(z_tau,40, tau_W0,40, tau_b0, h_a,DD, BB,DD,40, nullptr,nullptr);
    gemm_xwt<true,true,false><<<gP, 256, 0, stream>>>(h_a,DD, tau_W1,DD, tau_b1, h_b,DD, BB,DD,DD, nullptr,nullptr);
    tau_head<<<BB/4, 256, 0, stream>>>(h_b, tau_W2, taubG);
    gemm_xwt<true,true,false><<<gP, 256, 0, stream>>>(z_del,40, del_W0,40, del_b0, h_a,DD, BB,DD,40, nullptr,nullptr);
    gemm_xwt<true,true,false><<<gP, 256, 0, stream>>>(h_a,DD, del_W1,DD, del_b1, h_b,DD, BB,DD,DD, nullptr,nullptr);
    delta_head<<<BB, 256, 0, stream>>>(h_b, del_W2, deltaG);
  }

  const int iL = NLAY - 1;

  for (size_t b0 = 0; b0 < BB; b0 += CB) {
    const size_t cb = (BB - b0 < CB) ? (BB - b0) : CB;   // multiple of 64
    const int cm = (int)(cb * LL);                        // multiple of 1280
    const float* srcC  = src + b0*LL*FE;
    const float* meanC = meanG + b0*FE;
    const float* stdvC = stdvG + b0*FE;
    const float* taub  = taubG + b0;
    const float* delta = deltaG + b0*FE;

    const dim3 gEmb(8, cm/64);
    const dim3 gQKV(1536/128, cm/128);
    const dim3 gD(DD/128, cm/128);
    const dim3 gF1(FFD/128, cm/128);
    const dim3 gKV(1024/128, cm/128);
    const dim3 g19D(DD/128, (int)cb/64);
    const dim3 g19F(FFD/128, (int)cb/64);

    snorm_kernel<<<(int)((cb*LL*FE + 255)/256), 256, 0, stream>>>(srcC, meanC, stdvC, sbuf, (int)(cb*LL*FE));
    // embedding: xb = bf16(s @ W_feat^T + b_feat + pe)
    gemm_xwt<false,true,true><<<gEmb, 256, 0, stream>>>(sbuf,FE, W_feat,FE, b_feat, nullptr,DD, cm,DD,FE, pe, xb);

    // layers 0..NLAY-2 (full width)
    for (int i = 0; i < iL; ++i) {
      const size_t wOfs = (size_t)i * DD * DD;
      const size_t fOfs = (size_t)i * FFD * DD;
      bgemm<false,true,false><<<gQKV, 256, 0, stream>>>(xb,DD, Wqkvb + (size_t)i*1536*DD,DD, bqkv + i*1536, nullptr,0, qkvb,1536, DD);
      attn_kernel<<<(int)cb*HH, 256, 0, stream>>>(qkvb, taub, delta);
      // O-proj: xb = bf16(o @ Wo^T + bo + xb)  (o = qkvb cols 0..511)
      bgemm<false,true,true><<<gD, 256, 0, stream>>>(qkvb,1536, Wob+wOfs,DD, bo+i*DD, xb,DD, xb,DD, DD);
      ln_bf16_kernel<<<cm/4, 256, 0, stream>>>(xb, ln1_g+i*DD, ln1_b+i*DD);
      // FFN1: hb = relu(xb @ Wc1^T + bc1)  [cm,2048]
      bgemm<true,true,false><<<gF1, 256, 0, stream>>>(xb,DD, Wc1b+fOfs,DD, bc1+i*FFD, nullptr,0, hb,FFD, DD);
      // FFN2: xb = bf16(hb @ Wc2^T + bc2 + xb), K=2048
      bgemm<false,true,true><<<gD, 256, 0, stream>>>(hb,FFD, Wc2b+fOfs,FFD, bc2+i*DD, xb,DD, xb,DD, FFD);
      ln_bf16_kernel<<<cm/4, 256, 0, stream>>>(xb, ln2_g+i*DD, ln2_b+i*DD);
    }

    // last layer: only row l=19 feeds the output
    {
      const size_t wOfs = (size_t)iL * DD * DD;
      const size_t fOfs = (size_t)iL * FFD * DD;
      bgemm<false,true,false><<<gKV, 256, 0, stream>>>(xb,DD, Wqkvb + (size_t)iL*1536*DD + (size_t)512*DD,DD, bqkv + iL*1536 + 512, nullptr,0, kvb,1024, DD);
      bgemm64<false,true,false><<<g19D, 256, 0, stream>>>(xb + 19*DD, LL*DD, Wqkvb + (size_t)iL*1536*DD,DD, bqkv + iL*1536, nullptr,0, q19b,DD, DD);
      attn19_kernel<<<(int)cb*HH, 64, 0, stream>>>(kvb, q19b, o19b, taub, delta);
      bgemm64<false,true,true><<<g19D, 256, 0, stream>>>(o19b,DD, Wob+wOfs,DD, bo+iL*DD, xb + 19*DD, LL*DD, x19b,DD, DD);
      ln_bf16_kernel<<<(int)cb/4, 256, 0, stream>>>(x19b, ln1_g+iL*DD, ln1_b+iL*DD);
      bgemm64<true,true,false><<<g19F, 256, 0, stream>>>(x19b,DD, Wc1b+fOfs,DD, bc1+iL*FFD, nullptr,0, hb19,FFD, DD);
      bgemm64<false,true,true><<<g19D, 256, 0, stream>>>(hb19,FFD, Wc2b+fOfs,FFD, bc2+iL*DD, x19b,DD, x19b,DD, FFD);
      ln_bf16_kernel<<<(int)cb/4, 256, 0, stream>>>(x19b, ln2_g+iL*DD, ln2_b+iL*DD);
    }

    final_kernel<<<(int)cb, 64, 0, stream>>>(x19b, lnf_g, lnf_b, W_pre, b_pre, meanC, stdvC, W_dec, b_dec, out + b0);
  }
}